// Round 1
// baseline (4836.345 us; speedup 1.0000x reference)
//
#include <hip/hip_runtime.h>
#include <math.h>

#define BATCH 256
#define SEQ 26
#define TOK (BATCH*SEQ)   // 6656
#define DIM 512
#define HCH 256
#define NHEADS 8
#define NREL 8
#define HDIM 64
#define QKDIM 32

// ---------------------------------------------------------------------------
// conv (15x15 stride 15) as patch-GEMM + positional encoding + cls row
// grid (25, B), block 256 (one thread per out channel)
__global__ void conv_emb_kernel(const float* __restrict__ img,
                                const float* __restrict__ conv_w,
                                const float* __restrict__ conv_b,
                                const float* __restrict__ cls,
                                float* __restrict__ emb) {
    int pos = blockIdx.x;   // 0..24
    int b   = blockIdx.y;
    int oc  = threadIdx.x;  // 0..255
    __shared__ float patch[675];
    int ph = pos / 5, pw = pos % 5;
    for (int j = threadIdx.x; j < 675; j += 256) {
        int c = j / 225, rem = j % 225;
        int kh = rem / 15, kw = rem % 15;
        patch[j] = img[((b*3 + c)*75 + ph*15 + kh)*75 + pw*15 + kw];
    }
    __syncthreads();
    float acc = conv_b[oc];
    const float* wrow = conv_w + oc*675;
    #pragma unroll 5
    for (int j = 0; j < 675; ++j) acc += patch[j] * wrow[j];
    // pe[pos, oc]: uniform frequency exponent oc/128, sin for even oc, cos for odd
    float freq = powf(10000.0f, -(float)oc / 128.0f);
    float a = (float)pos * freq;
    float pe = 0.7310585786300049f * ((oc & 1) ? cosf(a) : sinf(a));
    emb[(b*SEQ + 1 + pos)*HCH + oc] = acc + pe;
    if (pos == 0) emb[(b*SEQ)*HCH + oc] = cls[oc];  // cls row, no pe
}

// ---------------------------------------------------------------------------
// per-batch question path: que = qst@qrep_w+qrep_b; quem = que@map_w[256:]+map_b
// grid B, block 256
__global__ void que_map_kernel(const float* __restrict__ qst,
                               const float* __restrict__ qrep_w,
                               const float* __restrict__ qrep_b,
                               const float* __restrict__ map_w,
                               const float* __restrict__ map_b,
                               float* __restrict__ quem) {
    int b = blockIdx.x;
    int t = threadIdx.x;
    __shared__ float que[HCH];
    float acc = qrep_b[t];
    for (int j = 0; j < 18; ++j) acc += qst[b*18 + j] * qrep_w[j*HCH + t];
    que[t] = acc;
    __syncthreads();
    for (int n = t; n < DIM; n += 256) {
        float a2 = map_b[n];
        for (int k = 0; k < HCH; ++k) a2 += que[k] * map_w[(HCH + k)*DIM + n];
        quem[b*DIM + n] = a2;
    }
}

// ---------------------------------------------------------------------------
// generic f32 tiled GEMM: C[M,N] = op(A[M,K] @ Bm[K,N] + bias)*alpha (+res)
// resmode: 0 none, 1 res[row*N+col], 2 res[(row/26)*N+col]
// M%64==0, N%64==0, K%16==0 guaranteed by caller.
__global__ void gemm_kernel(const float* __restrict__ A, const float* __restrict__ Bm,
                            const float* __restrict__ bias, const float* __restrict__ res,
                            float* __restrict__ C, int M, int N, int K,
                            int resmode, int relu, float alpha) {
    __shared__ float As[16][65];
    __shared__ float Bs[16][65];
    int tx = threadIdx.x, ty = threadIdx.y;   // 16x16
    int tid = ty*16 + tx;
    int bm = blockIdx.y * 64, bn = blockIdx.x * 64;
    float acc[4][4] = {};
    int am = tid >> 2;          // 0..63 (row in A tile)
    int ak = (tid & 3) * 4;     // k sub-offset
    int brow = tid >> 4;        // 0..15 (k row in B tile)
    int bcol = (tid & 15) * 4;  // col sub-offset
    for (int k0 = 0; k0 < K; k0 += 16) {
        float4 av = *(const float4*)&A[(size_t)(bm+am)*K + k0 + ak];
        As[ak+0][am] = av.x; As[ak+1][am] = av.y; As[ak+2][am] = av.z; As[ak+3][am] = av.w;
        float4 bv = *(const float4*)&Bm[(size_t)(k0+brow)*N + bn + bcol];
        Bs[brow][bcol+0] = bv.x; Bs[brow][bcol+1] = bv.y; Bs[brow][bcol+2] = bv.z; Bs[brow][bcol+3] = bv.w;
        __syncthreads();
        #pragma unroll
        for (int kk = 0; kk < 16; ++kk) {
            float ar[4], br[4];
            #pragma unroll
            for (int i = 0; i < 4; ++i) ar[i] = As[kk][ty*4+i];
            #pragma unroll
            for (int j = 0; j < 4; ++j) br[j] = Bs[kk][tx*4+j];
            #pragma unroll
            for (int i = 0; i < 4; ++i)
                #pragma unroll
                for (int j = 0; j < 4; ++j)
                    acc[i][j] += ar[i]*br[j];
        }
        __syncthreads();
    }
    #pragma unroll
    for (int i = 0; i < 4; ++i) {
        int row = bm + ty*4 + i;
        #pragma unroll
        for (int j = 0; j < 4; ++j) {
            int col = bn + tx*4 + j;
            float v = acc[i][j] + (bias ? bias[col] : 0.0f);
            v *= alpha;
            if (relu) v = fmaxf(v, 0.0f);
            if (resmode == 1)      v += res[(size_t)row*N + col];
            else if (resmode == 2) v += res[(size_t)(row/SEQ)*N + col];
            C[(size_t)row*N + col] = v;
        }
    }
}

// ---------------------------------------------------------------------------
// LayerNorm over D=512; grid TOK, block 256 (2 elems/thread)
__global__ void ln_kernel(const float* __restrict__ x, const float* __restrict__ g,
                          const float* __restrict__ bta, float* __restrict__ out) {
    int t = blockIdx.x;
    int tid = threadIdx.x;
    const float* xr = x + (size_t)t*DIM;
    float v0 = xr[tid], v1 = xr[tid+256];
    float s = v0 + v1, sq = v0*v0 + v1*v1;
    __shared__ float rs[4], rq[4];
    for (int off = 32; off; off >>= 1) { s += __shfl_down(s, off); sq += __shfl_down(sq, off); }
    int wid = tid >> 6, lane = tid & 63;
    if (lane == 0) { rs[wid] = s; rq[wid] = sq; }
    __syncthreads();
    __shared__ float mean_s, rstd_s;
    if (tid == 0) {
        float ts = rs[0]+rs[1]+rs[2]+rs[3], tq = rq[0]+rq[1]+rq[2]+rq[3];
        float m = ts / DIM;
        float var = tq / DIM - m*m;
        mean_s = m; rstd_s = rsqrtf(var + 1e-5f);
    }
    __syncthreads();
    float m = mean_s, r = rstd_s;
    out[(size_t)t*DIM + tid]       = (v0 - m)*r*g[tid]       + bta[tid];
    out[(size_t)t*DIM + tid + 256] = (v1 - m)*r*g[tid+256]   + bta[tid+256];
}

// ---------------------------------------------------------------------------
// score = softmax_k(q . k) per (b,h); q pre-scaled by 1/8.
// grid (NHEADS, B), block 256
__global__ void score_kernel(const float* __restrict__ q, const float* __restrict__ k,
                             float* __restrict__ score) {
    int h = blockIdx.x, b = blockIdx.y;
    __shared__ float qs[SEQ*HDIM], ks[SEQ*HDIM], st[SEQ*SEQ];
    int tid = threadIdx.x;
    for (int idx = tid; idx < SEQ*HDIM; idx += 256) {
        int s_ = idx >> 6, d = idx & 63;
        qs[idx] = q[(size_t)(b*SEQ + s_)*DIM + h*HDIM + d];
        ks[idx] = k[(size_t)(b*SEQ + s_)*DIM + h*HDIM + d];
    }
    __syncthreads();
    for (int idx = tid; idx < SEQ*SEQ; idx += 256) {
        int qi = idx / SEQ, ki = idx % SEQ;
        float acc = 0.0f;
        #pragma unroll
        for (int d = 0; d < HDIM; ++d) acc += qs[qi*HDIM+d]*ks[ki*HDIM+d];
        st[idx] = acc;
    }
    __syncthreads();
    if (tid < SEQ) {
        float m = -1e30f;
        for (int j = 0; j < SEQ; ++j) m = fmaxf(m, st[tid*SEQ+j]);
        float den = 0.0f;
        for (int j = 0; j < SEQ; ++j) den += expf(st[tid*SEQ+j]-m);
        float inv = 1.0f/den;
        for (int j = 0; j < SEQ; ++j)
            score[(size_t)((b*NHEADS+h)*SEQ + tid)*SEQ + j] = expf(st[tid*SEQ+j]-m)*inv;
    }
}

// ---------------------------------------------------------------------------
// fused: out[r,d] = sum_k score[h,q,k]*v[k,r,d]; e[r]=out[r,:].sw; comp=softmax_r(e);
// o[h,d] = sum_r comp[r]*out[r,d].   (qv & score_b cancel in softmax over r)
// grid (SEQ, B), block 512 (t = r*64+d; one wave per r)
__global__ void attn_comp_kernel(const float* __restrict__ v, const float* __restrict__ score,
                                 const float* __restrict__ score_w, float* __restrict__ attn_o) {
    int qpos = blockIdx.x, b = blockIdx.y;
    int t = threadIdx.x;
    __shared__ float vs[SEQ][DIM];
    __shared__ float ss[NHEADS][SEQ];
    __shared__ float sw[HDIM];
    __shared__ float es[NREL];
    __shared__ float wsum[DIM];
    for (int kk = 0; kk < SEQ; ++kk) vs[kk][t] = v[(size_t)(b*SEQ+kk)*DIM + t];
    if (t < NHEADS*SEQ) { int h = t / SEQ, kk = t % SEQ;
        ss[h][kk] = score[(size_t)((b*NHEADS+h)*SEQ + qpos)*SEQ + kk]; }
    if (t < HDIM) sw[t] = score_w[QKDIM + t];
    __syncthreads();
    int r = t >> 6, d = t & 63;
    for (int h = 0; h < NHEADS; ++h) {
        float acc = 0.0f;
        #pragma unroll
        for (int kk = 0; kk < SEQ; ++kk) acc += ss[h][kk]*vs[kk][t];
        float ew = acc * sw[d];
        for (int off = 32; off; off >>= 1) ew += __shfl_down(ew, off);
        if (d == 0) es[r] = ew;
        __syncthreads();
        float m = es[0];
        #pragma unroll
        for (int i = 1; i < NREL; ++i) m = fmaxf(m, es[i]);
        float den = 0.0f;
        #pragma unroll
        for (int i = 0; i < NREL; ++i) den += expf(es[i]-m);
        float comp = expf(es[r]-m)/den;
        wsum[t] = comp*acc;
        __syncthreads();
        if (t < HDIM) {
            float o = 0.0f;
            #pragma unroll
            for (int i = 0; i < NREL; ++i) o += wsum[i*HDIM + t];
            attn_o[(size_t)(b*SEQ+qpos)*DIM + h*HDIM + t] = o;
        }
        __syncthreads();
    }
}

// ---------------------------------------------------------------------------
// head: y = x[:,0,:]@out_w+out_b; log_softmax. grid B, block 64
__global__ void head_kernel(const float* __restrict__ x, const float* __restrict__ out_w,
                            const float* __restrict__ out_b, float* __restrict__ y) {
    int b = blockIdx.x;
    int t = threadIdx.x;
    __shared__ float yv[10];
    if (t < 10) {
        float acc = out_b[t];
        const float* xr = x + (size_t)(b*SEQ)*DIM;
        for (int dd = 0; dd < DIM; ++dd) acc += xr[dd]*out_w[dd*10 + t];
        yv[t] = acc;
    }
    __syncthreads();
    if (t < 10) {
        float m = yv[0];
        for (int i = 1; i < 10; ++i) m = fmaxf(m, yv[i]);
        float den = 0.0f;
        for (int i = 0; i < 10; ++i) den += expf(yv[i]-m);
        y[b*10 + t] = yv[t] - m - logf(den);
    }
}

// ---------------------------------------------------------------------------
extern "C" void kernel_launch(void* const* d_in, const int* in_sizes, int n_in,
                              void* d_out, int out_size, void* d_ws, size_t ws_size,
                              hipStream_t stream) {
    const float* img      = (const float*)d_in[0];
    const float* qst      = (const float*)d_in[1];
    const float* conv_w   = (const float*)d_in[2];
    const float* conv_b   = (const float*)d_in[3];
    const float* qrep_w   = (const float*)d_in[4];
    const float* qrep_b   = (const float*)d_in[5];
    const float* cls_tok  = (const float*)d_in[6];
    const float* map_w    = (const float*)d_in[7];
    const float* map_b    = (const float*)d_in[8];
    const float* norm1_g  = (const float*)d_in[9];
    const float* norm1_b  = (const float*)d_in[10];
    const float* norm2_g  = (const float*)d_in[11];
    const float* norm2_b  = (const float*)d_in[12];
    const float* q_w      = (const float*)d_in[13];
    const float* q_b      = (const float*)d_in[14];
    const float* k_w      = (const float*)d_in[15];
    const float* k_b      = (const float*)d_in[16];
    const float* v_w      = (const float*)d_in[17];
    const float* v_b      = (const float*)d_in[18];
    // d_in[19] qv_w, d_in[20] qv_b: provably cancel in the r-softmax — unused
    const float* score_w  = (const float*)d_in[21];
    // d_in[22] score_b: constant along softmax axis — unused
    const float* final_w  = (const float*)d_in[23];
    const float* final_b  = (const float*)d_in[24];
    const float* ffn1_w   = (const float*)d_in[25];
    const float* ffn1_b   = (const float*)d_in[26];
    const float* ffn2_w   = (const float*)d_in[27];
    const float* ffn2_b   = (const float*)d_in[28];
    const float* out_w    = (const float*)d_in[29];
    const float* out_b    = (const float*)d_in[30];

    float* ws = (float*)d_ws;
    // workspace layout (floats)
    float* emb    = ws;                         // TOK*HCH      = 1,703,936
    float* quem   = emb   + (size_t)TOK*HCH;    // BATCH*DIM    =   131,072
    float* x      = quem  + (size_t)BATCH*DIM;  // TOK*DIM      = 3,407,872
    float* h      = x     + (size_t)TOK*DIM;
    float* qbuf   = h     + (size_t)TOK*DIM;
    float* kbuf   = qbuf  + (size_t)TOK*DIM;
    float* vbuf   = kbuf  + (size_t)TOK*DIM;
    float* scoreb = vbuf  + (size_t)TOK*DIM;    // B*NH*S*S     = 1,384,448
    float* attn_o = scoreb+ (size_t)BATCH*NHEADS*SEQ*SEQ;
    float* ffbuf  = qbuf;                       // aliases q+k (dead during FFN), TOK*1024

    dim3 gblk(16,16);

    // patch embedding + pe + cls
    conv_emb_kernel<<<dim3(25, BATCH), 256, 0, stream>>>(img, conv_w, conv_b, cls_tok, emb);
    // question path folded through map_w bottom half (+map_b)
    que_map_kernel<<<BATCH, 256, 0, stream>>>(qst, qrep_w, qrep_b, map_w, map_b, quem);
    // x = emb @ map_w[:256] + quem (per-batch)   [bias folded into quem]
    gemm_kernel<<<dim3(DIM/64, TOK/64), gblk, 0, stream>>>(
        emb, map_w, nullptr, quem, x, TOK, DIM, HCH, 2, 0, 1.0f);

    for (int it = 0; it < 4; ++it) {
        ln_kernel<<<TOK, 256, 0, stream>>>(x, norm1_g, norm1_b, h);
        gemm_kernel<<<dim3(DIM/64, TOK/64), gblk, 0, stream>>>(
            h, q_w, q_b, nullptr, qbuf, TOK, DIM, DIM, 0, 0, 0.125f);   // /sqrt(64)
        gemm_kernel<<<dim3(DIM/64, TOK/64), gblk, 0, stream>>>(
            h, k_w, k_b, nullptr, kbuf, TOK, DIM, DIM, 0, 0, 1.0f);
        gemm_kernel<<<dim3(DIM/64, TOK/64), gblk, 0, stream>>>(
            h, v_w, v_b, nullptr, vbuf, TOK, DIM, DIM, 0, 0, 1.0f);
        score_kernel<<<dim3(NHEADS, BATCH), 256, 0, stream>>>(qbuf, kbuf, scoreb);
        attn_comp_kernel<<<dim3(SEQ, BATCH), 512, 0, stream>>>(vbuf, scoreb, score_w, attn_o);
        gemm_kernel<<<dim3(DIM/64, TOK/64), gblk, 0, stream>>>(
            attn_o, final_w, final_b, x, x, TOK, DIM, DIM, 1, 0, 1.0f); // +residual
        ln_kernel<<<TOK, 256, 0, stream>>>(x, norm2_g, norm2_b, h);
        gemm_kernel<<<dim3(1024/64, TOK/64), gblk, 0, stream>>>(
            h, ffn1_w, ffn1_b, nullptr, ffbuf, TOK, 1024, DIM, 0, 1, 1.0f); // relu
        gemm_kernel<<<dim3(DIM/64, TOK/64), gblk, 0, stream>>>(
            ffbuf, ffn2_w, ffn2_b, x, x, TOK, DIM, 1024, 1, 0, 1.0f);   // +residual
    }

    head_kernel<<<BATCH, 64, 0, stream>>>(x, out_w, out_b, (float*)d_out);
}

// Round 2
// 1428.873 us; speedup vs baseline: 3.3847x; 3.3847x over previous
//
#include <hip/hip_runtime.h>
#include <math.h>

#define NB 256
#define SEQ 26
#define TOK (NB*SEQ)   // 6656
#define DIM 512

typedef unsigned short u16;
typedef __attribute__((ext_vector_type(8))) short short8_t;
typedef __attribute__((ext_vector_type(4))) float floatx4;

__device__ inline u16 f2bf(float f) {
    union { float f; unsigned u; } v; v.f = f;
    unsigned r = v.u + 0x7fffu + ((v.u >> 16) & 1u);
    return (u16)(r >> 16);
}

// ---------------------------------------------------------------------------
// Weight transpose+convert: Wt[n*K + k] = bf16(W[k*N + n]).  grid N, block 256.
__global__ void wtrans(const float* __restrict__ W, u16* __restrict__ Wt, int K, int N) {
    int n = blockIdx.x;
    for (int k = threadIdx.x; k < K; k += 256)
        Wt[(size_t)n*K + k] = f2bf(W[(size_t)k*N + n]);
}

// conv_w [256][675] -> bf16 [256][704] zero-padded (already [N][K] layout)
__global__ void convw_bf(const float* __restrict__ W, u16* __restrict__ Wb) {
    int oc = blockIdx.x;
    for (int j = threadIdx.x; j < 704; j += 256)
        Wb[(size_t)oc*704 + j] = (j < 675) ? f2bf(W[(size_t)oc*675 + j]) : (u16)0;
}

__global__ void concat3(const float* __restrict__ a, const float* __restrict__ b,
                        const float* __restrict__ c, float* __restrict__ o) {
    int t = blockIdx.x*256 + threadIdx.x;  // 0..1535
    o[t] = t < 512 ? a[t] : (t < 1024 ? b[t-512] : c[t-1024]);
}

// ---------------------------------------------------------------------------
// im2col: P[(b*25+pos)][j] bf16, K padded to 704
__global__ void im2col_kernel(const float* __restrict__ img, u16* __restrict__ P) {
    int ri = blockIdx.x;               // 0..6399
    int b = ri / 25, pos = ri % 25, ph = pos/5, pw = pos%5;
    for (int j = threadIdx.x; j < 704; j += 256) {
        float v = 0.f;
        if (j < 675) {
            int c = j / 225, rem = j % 225, kh = rem/15, kw = rem%15;
            v = img[(size_t)((b*3+c)*75 + ph*15 + kh)*75 + pw*15 + kw];
        }
        P[(size_t)ri*704 + j] = f2bf(v);
    }
}

// emb rows: cls row + (convout + pe) rows, bf16
__global__ void pe_cls_kernel(const float* __restrict__ co, const float* __restrict__ cls,
                              u16* __restrict__ emb) {
    int t = blockIdx.x;                // 0..6655
    int b = t / SEQ, s = t % SEQ;
    int oc = threadIdx.x;              // 0..255
    float v;
    if (s == 0) v = cls[oc];
    else {
        int pos = s - 1;
        float freq = __powf(10000.0f, -(float)oc / 128.0f);
        float a = (float)pos * freq;
        float pe = 0.7310585786300049f * ((oc & 1) ? __cosf(a) : __sinf(a));
        v = co[(size_t)(b*25+pos)*256 + oc] + pe;
    }
    emb[(size_t)t*256 + oc] = f2bf(v);
}

// ---------------------------------------------------------------------------
// bf16 MFMA GEMM: C[M,N] = op(A[M,K] @ B + bias)*alpha [+res],  B given as Bt[N,K].
// 128x128 tile, BK=64, 256 threads (4 waves, 2x2), XOR-swizzled LDS.
// RESMODE: 0 none, 1 res[row*N+col], 2 res[(row/26)*N+col]. OUTBF: write bf16.
template<int RESMODE, int RELU, int OUTBF>
__global__ void mfma_gemm(const u16* __restrict__ A, const u16* __restrict__ Bt,
                          const float* __restrict__ bias, const float* __restrict__ res,
                          void* __restrict__ Cout, int M, int N, int K, float alpha) {
    __shared__ u16 As[128*64];
    __shared__ u16 Bs[128*64];
    const int tid = threadIdx.x;
    const int lane = tid & 63;
    const int w = tid >> 6;
    const int wr = (w >> 1) * 64, wc = (w & 1) * 64;
    const int bm = blockIdx.y * 128, bn = blockIdx.x * 128;

    floatx4 acc[4][4] = {{{0.f,0.f,0.f,0.f}}};
    #pragma unroll
    for (int mi = 0; mi < 4; ++mi)
        #pragma unroll
        for (int ni = 0; ni < 4; ++ni)
            acc[mi][ni] = (floatx4){0.f,0.f,0.f,0.f};

    for (int k0 = 0; k0 < K; k0 += 64) {
        short8_t ar[4], br[4];
        #pragma unroll
        for (int s = 0; s < 4; ++s) {
            int ci = s*256 + tid;
            int row = ci >> 3, ch = ci & 7;
            ar[s] = *(const short8_t*)&A [(size_t)(bm+row)*K + k0 + ch*8];
            br[s] = *(const short8_t*)&Bt[(size_t)(bn+row)*K + k0 + ch*8];
        }
        __syncthreads();   // previous iteration's reads done
        #pragma unroll
        for (int s = 0; s < 4; ++s) {
            int ci = s*256 + tid;
            int row = ci >> 3, ch = ci & 7;
            int off = row*64 + ((ch ^ (row & 7)) * 8);
            *(short8_t*)&As[off] = ar[s];
            *(short8_t*)&Bs[off] = br[s];
        }
        __syncthreads();
        #pragma unroll
        for (int kk = 0; kk < 2; ++kk) {
            short8_t af[4], bf[4];
            #pragma unroll
            for (int mi = 0; mi < 4; ++mi) {
                int row = wr + mi*16 + (lane & 15);
                int ch = kk*4 + (lane >> 4);
                af[mi] = *(const short8_t*)&As[row*64 + ((ch ^ (row & 7))*8)];
            }
            #pragma unroll
            for (int ni = 0; ni < 4; ++ni) {
                int rowb = wc + ni*16 + (lane & 15);
                int ch = kk*4 + (lane >> 4);
                bf[ni] = *(const short8_t*)&Bs[rowb*64 + ((ch ^ (rowb & 7))*8)];
            }
            #pragma unroll
            for (int mi = 0; mi < 4; ++mi)
                #pragma unroll
                for (int ni = 0; ni < 4; ++ni)
                    acc[mi][ni] = __builtin_amdgcn_mfma_f32_16x16x32_bf16(
                        af[mi], bf[ni], acc[mi][ni], 0, 0, 0);
        }
    }

    #pragma unroll
    for (int mi = 0; mi < 4; ++mi) {
        #pragma unroll
        for (int ni = 0; ni < 4; ++ni) {
            int col = bn + wc + ni*16 + (lane & 15);
            float bv = bias ? bias[col] : 0.0f;
            #pragma unroll
            for (int r = 0; r < 4; ++r) {
                int row = bm + wr + mi*16 + (lane >> 4)*4 + r;
                float v = (acc[mi][ni][r] + bv) * alpha;
                if (RELU) v = fmaxf(v, 0.f);
                if (RESMODE == 1)      v += res[(size_t)row*N + col];
                else if (RESMODE == 2) v += res[(size_t)(row/SEQ)*N + col];
                if (OUTBF) ((u16*)Cout)[(size_t)row*N + col] = f2bf(v);
                else       ((float*)Cout)[(size_t)row*N + col] = v;
            }
        }
    }
}

// ---------------------------------------------------------------------------
// per-batch question path: que = qst@qrep_w+qrep_b; quem = que@map_w[256:]+map_b
__global__ void que_map_kernel(const float* __restrict__ qst,
                               const float* __restrict__ qrep_w,
                               const float* __restrict__ qrep_b,
                               const float* __restrict__ map_w,
                               const float* __restrict__ map_b,
                               float* __restrict__ quem) {
    int b = blockIdx.x;
    int t = threadIdx.x;
    __shared__ float que[256];
    float acc = qrep_b[t];
    for (int j = 0; j < 18; ++j) acc += qst[b*18 + j] * qrep_w[j*256 + t];
    que[t] = acc;
    __syncthreads();
    for (int n = t; n < DIM; n += 256) {
        float a2 = map_b[n];
        for (int k = 0; k < 256; ++k) a2 += que[k] * map_w[(256 + k)*DIM + n];
        quem[b*DIM + n] = a2;
    }
}

// ---------------------------------------------------------------------------
// LayerNorm over D=512, bf16 out; grid TOK, block 256
__global__ void ln_kernel(const float* __restrict__ x, const float* __restrict__ g,
                          const float* __restrict__ bta, u16* __restrict__ out) {
    int t = blockIdx.x;
    int tid = threadIdx.x;
    const float* xr = x + (size_t)t*DIM;
    float v0 = xr[tid], v1 = xr[tid+256];
    float s = v0 + v1, sq = v0*v0 + v1*v1;
    __shared__ float rs[4], rq[4];
    for (int off = 32; off; off >>= 1) { s += __shfl_down(s, off); sq += __shfl_down(sq, off); }
    int wid = tid >> 6, lane = tid & 63;
    if (lane == 0) { rs[wid] = s; rq[wid] = sq; }
    __syncthreads();
    __shared__ float mean_s, rstd_s;
    if (tid == 0) {
        float ts = rs[0]+rs[1]+rs[2]+rs[3], tq = rq[0]+rq[1]+rq[2]+rq[3];
        float m = ts / DIM;
        float var = tq / DIM - m*m;
        mean_s = m; rstd_s = rsqrtf(var + 1e-5f);
    }
    __syncthreads();
    float m = mean_s, r = rstd_s;
    out[(size_t)t*DIM + tid]       = f2bf((v0 - m)*r*g[tid]     + bta[tid]);
    out[(size_t)t*DIM + tid + 256] = f2bf((v1 - m)*r*g[tid+256] + bta[tid+256]);
}

// ---------------------------------------------------------------------------
// score = softmax_k(q.k /8) per (b,h), q/k from fused qkv [tok][1536]
__global__ void score_kernel(const float* __restrict__ qkv, float* __restrict__ score) {
    int h = blockIdx.x, b = blockIdx.y;
    __shared__ float qs[SEQ*64], ks[SEQ*64], st[SEQ*SEQ];
    int tid = threadIdx.x;
    for (int idx = tid; idx < SEQ*64; idx += 256) {
        int s_ = idx >> 6, d = idx & 63;
        qs[idx] = qkv[(size_t)(b*SEQ+s_)*1536 + h*64 + d] * 0.125f;
        ks[idx] = qkv[(size_t)(b*SEQ+s_)*1536 + 512 + h*64 + d];
    }
    __syncthreads();
    for (int idx = tid; idx < SEQ*SEQ; idx += 256) {
        int qi = idx / SEQ, ki = idx % SEQ;
        float acc = 0.0f;
        #pragma unroll
        for (int d = 0; d < 64; ++d) acc += qs[qi*64+d]*ks[ki*64+d];
        st[idx] = acc;
    }
    __syncthreads();
    if (tid < SEQ) {
        float m = -1e30f;
        for (int j = 0; j < SEQ; ++j) m = fmaxf(m, st[tid*SEQ+j]);
        float den = 0.0f;
        for (int j = 0; j < SEQ; ++j) den += __expf(st[tid*SEQ+j]-m);
        float inv = 1.0f/den;
        for (int j = 0; j < SEQ; ++j)
            score[(size_t)((b*8+h)*SEQ + tid)*SEQ + j] = __expf(st[tid*SEQ+j]-m)*inv;
    }
}

// ---------------------------------------------------------------------------
// fused second attention stage (qv & score_b provably cancel in the r-softmax)
__global__ void attn_comp_kernel(const float* __restrict__ qkv, const float* __restrict__ score,
                                 const float* __restrict__ score_w, u16* __restrict__ attn_o) {
    int qpos = blockIdx.x, b = blockIdx.y;
    int t = threadIdx.x;   // 512
    __shared__ float vs[SEQ][DIM];
    __shared__ float ss[8][SEQ];
    __shared__ float sw[64];
    __shared__ float es[8];
    __shared__ float wsum[DIM];
    for (int kk = 0; kk < SEQ; ++kk) vs[kk][t] = qkv[(size_t)(b*SEQ+kk)*1536 + 1024 + t];
    if (t < 8*SEQ) ss[t/SEQ][t%SEQ] = score[(size_t)((b*8 + t/SEQ)*SEQ + qpos)*SEQ + (t%SEQ)];
    if (t < 64) sw[t] = score_w[32 + t];
    __syncthreads();
    int r = t >> 6, d = t & 63;
    for (int h = 0; h < 8; ++h) {
        float acc = 0.f;
        #pragma unroll
        for (int kk = 0; kk < SEQ; ++kk) acc += ss[h][kk]*vs[kk][t];
        float ew = acc * sw[d];
        #pragma unroll
        for (int off = 32; off; off >>= 1) ew += __shfl_down(ew, off);
        if (d == 0) es[r] = ew;
        __syncthreads();
        float m = es[0];
        #pragma unroll
        for (int i = 1; i < 8; ++i) m = fmaxf(m, es[i]);
        float den = 0.f;
        #pragma unroll
        for (int i = 0; i < 8; ++i) den += __expf(es[i]-m);
        float comp = __expf(es[r]-m)/den;
        wsum[t] = comp*acc;
        __syncthreads();
        if (t < 64) {
            float o = 0.f;
            #pragma unroll
            for (int i = 0; i < 8; ++i) o += wsum[i*64 + t];
            attn_o[(size_t)(b*SEQ+qpos)*DIM + h*64 + t] = f2bf(o);
        }
        __syncthreads();
    }
}

// ---------------------------------------------------------------------------
__global__ void head_kernel(const float* __restrict__ x, const float* __restrict__ out_w,
                            const float* __restrict__ out_b, float* __restrict__ y) {
    int b = blockIdx.x;
    int t = threadIdx.x;
    __shared__ float yv[10];
    if (t < 10) {
        float acc = out_b[t];
        const float* xr = x + (size_t)(b*SEQ)*DIM;
        for (int dd = 0; dd < DIM; ++dd) acc += xr[dd]*out_w[dd*10 + t];
        yv[t] = acc;
    }
    __syncthreads();
    if (t < 10) {
        float m = yv[0];
        for (int i = 1; i < 10; ++i) m = fmaxf(m, yv[i]);
        float den = 0.0f;
        for (int i = 0; i < 10; ++i) den += expf(yv[i]-m);
        y[b*10 + t] = yv[t] - m - logf(den);
    }
}

// ---------------------------------------------------------------------------
extern "C" void kernel_launch(void* const* d_in, const int* in_sizes, int n_in,
                              void* d_out, int out_size, void* d_ws, size_t ws_size,
                              hipStream_t stream) {
    const float* img      = (const float*)d_in[0];
    const float* qst      = (const float*)d_in[1];
    const float* conv_w   = (const float*)d_in[2];
    const float* conv_b   = (const float*)d_in[3];
    const float* qrep_w   = (const float*)d_in[4];
    const float* qrep_b   = (const float*)d_in[5];
    const float* cls_tok  = (const float*)d_in[6];
    const float* map_w    = (const float*)d_in[7];
    const float* map_b    = (const float*)d_in[8];
    const float* norm1_g  = (const float*)d_in[9];
    const float* norm1_b  = (const float*)d_in[10];
    const float* norm2_g  = (const float*)d_in[11];
    const float* norm2_b  = (const float*)d_in[12];
    const float* q_w      = (const float*)d_in[13];
    const float* q_b      = (const float*)d_in[14];
    const float* k_w      = (const float*)d_in[15];
    const float* k_b      = (const float*)d_in[16];
    const float* v_w      = (const float*)d_in[17];
    const float* v_b      = (const float*)d_in[18];
    // d_in[19] qv_w, d_in[20] qv_b: cancel in r-softmax — unused
    const float* score_w  = (const float*)d_in[21];
    // d_in[22] score_b: constant along softmax axis — unused
    const float* final_w  = (const float*)d_in[23];
    const float* final_b  = (const float*)d_in[24];
    const float* ffn1_w   = (const float*)d_in[25];
    const float* ffn1_b   = (const float*)d_in[26];
    const float* ffn2_w   = (const float*)d_in[27];
    const float* ffn2_b   = (const float*)d_in[28];
    const float* out_w    = (const float*)d_in[29];
    const float* out_b    = (const float*)d_in[30];

    float* ws = (float*)d_ws;
    size_t o = 0;
    float* x    = ws + o;       o += (size_t)TOK*DIM;        // 3,407,872
    u16* qkvT   = (u16*)(ws+o); o += (size_t)1536*512/2;     // [1536][512]
    u16* finT   = (u16*)(ws+o); o += (size_t)512*512/2;
    u16* f1T    = (u16*)(ws+o); o += (size_t)1024*512/2;
    u16* f2T    = (u16*)(ws+o); o += (size_t)512*1024/2;
    u16* mapT   = (u16*)(ws+o); o += (size_t)512*256/2;
    u16* cwT    = (u16*)(ws+o); o += (size_t)256*704/2;
    float* qkvb = ws + o;       o += 1536;
    float* r2   = ws + o;
    // phase-2 layout in r2
    u16*  h_bf    = (u16*)r2;
    float* qkv    = r2 + (size_t)TOK*DIM/2;
    float* scoreb = qkv + (size_t)TOK*1536;
    u16*  attn_obf= (u16*)(scoreb + (size_t)NB*8*SEQ*SEQ);
    u16*  ffbuf   = (u16*)qkv;                     // alias (qkv dead during FFN)
    // phase-1 aliases r2
    u16*  Pbuf    = (u16*)r2;                      // 6400*704 bf16
    float* convout= r2 + (size_t)6400*704/2;
    u16*  emb_bf  = (u16*)(convout + (size_t)6400*256);
    float* quem   = convout + (size_t)6400*256 + (size_t)TOK*256/2;

    // ---- per-launch weight conversion (bf16, transposed to [N][K]) ----
    wtrans<<<512, 256, 0, stream>>>(q_w,     qkvT,              512, 512);
    wtrans<<<512, 256, 0, stream>>>(k_w,     qkvT + 512*512,    512, 512);
    wtrans<<<512, 256, 0, stream>>>(v_w,     qkvT + 1024*512,   512, 512);
    wtrans<<<512, 256, 0, stream>>>(final_w, finT,              512, 512);
    wtrans<<<1024,256, 0, stream>>>(ffn1_w,  f1T,               512, 1024);
    wtrans<<<512, 256, 0, stream>>>(ffn2_w,  f2T,               1024, 512);
    wtrans<<<512, 256, 0, stream>>>(map_w,   mapT,              256, 512);
    convw_bf<<<256, 256, 0, stream>>>(conv_w, cwT);
    concat3<<<6, 256, 0, stream>>>(q_b, k_b, v_b, qkvb);

    // ---- phase 1: embedding ----
    im2col_kernel<<<6400, 256, 0, stream>>>(img, Pbuf);
    que_map_kernel<<<NB, 256, 0, stream>>>(qst, qrep_w, qrep_b, map_w, map_b, quem);
    mfma_gemm<0,0,0><<<dim3(2,50), 256, 0, stream>>>(
        Pbuf, cwT, conv_b, nullptr, convout, 6400, 256, 704, 1.0f);
    pe_cls_kernel<<<TOK, 256, 0, stream>>>(convout, cls_tok, emb_bf);
    mfma_gemm<2,0,0><<<dim3(4,52), 256, 0, stream>>>(
        emb_bf, mapT, nullptr, quem, x, TOK, 512, 256, 1.0f);

    // ---- phase 2: 4 transformer iterations ----
    for (int it = 0; it < 4; ++it) {
        ln_kernel<<<TOK, 256, 0, stream>>>(x, norm1_g, norm1_b, h_bf);
        mfma_gemm<0,0,0><<<dim3(12,52), 256, 0, stream>>>(
            h_bf, qkvT, qkvb, nullptr, qkv, TOK, 1536, 512, 1.0f);
        score_kernel<<<dim3(8,NB), 256, 0, stream>>>(qkv, scoreb);
        attn_comp_kernel<<<dim3(SEQ,NB), 512, 0, stream>>>(qkv, scoreb, score_w, attn_obf);
        mfma_gemm<1,0,0><<<dim3(4,52), 256, 0, stream>>>(
            attn_obf, finT, final_b, x, x, TOK, 512, 512, 1.0f);
        ln_kernel<<<TOK, 256, 0, stream>>>(x, norm2_g, norm2_b, h_bf);
        mfma_gemm<0,1,1><<<dim3(8,52), 256, 0, stream>>>(
            h_bf, f1T, ffn1_b, nullptr, ffbuf, TOK, 1024, 512, 1.0f);
        mfma_gemm<1,0,0><<<dim3(4,52), 256, 0, stream>>>(
            ffbuf, f2T, ffn2_b, x, x, TOK, 512, 1024, 1.0f);
    }

    head_kernel<<<NB, 64, 0, stream>>>(x, out_w, out_b, (float*)d_out);
}

// Round 3
// 829.561 us; speedup vs baseline: 5.8300x; 1.7224x over previous
//
#include <hip/hip_runtime.h>
#include <math.h>

#define NB 256
#define SEQ 26
#define TOK (NB*SEQ)   // 6656
#define DIM 512

typedef unsigned short u16;
typedef __attribute__((ext_vector_type(8))) short short8_t;
typedef __attribute__((ext_vector_type(4))) float floatx4;

__device__ inline u16 f2bf(float f) {
    union { float f; unsigned u; } v; v.f = f;
    unsigned r = v.u + 0x7fffu + ((v.u >> 16) & 1u);
    return (u16)(r >> 16);
}
__device__ inline float bf2f(u16 u) {
    union { unsigned u; float f; } v; v.u = ((unsigned)u) << 16; return v.f;
}

// ---------------------------------------------------------------------------
// Weight transpose+convert: Wt[n*K + k] = bf16(W[k*N + n]).  grid N, block 256.
__global__ void wtrans(const float* __restrict__ W, u16* __restrict__ Wt, int K, int N) {
    int n = blockIdx.x;
    for (int k = threadIdx.x; k < K; k += 256)
        Wt[(size_t)n*K + k] = f2bf(W[(size_t)k*N + n]);
}

// conv_w [256][675] -> bf16 [256][704] zero-padded (already [N][K] layout)
__global__ void convw_bf(const float* __restrict__ W, u16* __restrict__ Wb) {
    int oc = blockIdx.x;
    for (int j = threadIdx.x; j < 704; j += 256)
        Wb[(size_t)oc*704 + j] = (j < 675) ? f2bf(W[(size_t)oc*675 + j]) : (u16)0;
}

__global__ void concat3(const float* __restrict__ a, const float* __restrict__ b,
                        const float* __restrict__ c, float* __restrict__ o) {
    int t = blockIdx.x*256 + threadIdx.x;  // 0..1535
    o[t] = t < 512 ? a[t] : (t < 1024 ? b[t-512] : c[t-1024]);
}

// ---------------------------------------------------------------------------
// im2col: P[(b*25+pos)][j] bf16, K padded to 704
__global__ void im2col_kernel(const float* __restrict__ img, u16* __restrict__ P) {
    int ri = blockIdx.x;               // 0..6399
    int b = ri / 25, pos = ri % 25, ph = pos/5, pw = pos%5;
    for (int j = threadIdx.x; j < 704; j += 256) {
        float v = 0.f;
        if (j < 675) {
            int c = j / 225, rem = j % 225, kh = rem/15, kw = rem%15;
            v = img[(size_t)((b*3+c)*75 + ph*15 + kh)*75 + pw*15 + kw];
        }
        P[(size_t)ri*704 + j] = f2bf(v);
    }
}

// emb rows: cls row + (convout + pe) rows, bf16
__global__ void pe_cls_kernel(const float* __restrict__ co, const float* __restrict__ cls,
                              u16* __restrict__ emb) {
    int t = blockIdx.x;                // 0..6655
    int b = t / SEQ, s = t % SEQ;
    int oc = threadIdx.x;              // 0..255
    float v;
    if (s == 0) v = cls[oc];
    else {
        int pos = s - 1;
        float freq = __powf(10000.0f, -(float)oc / 128.0f);
        float a = (float)pos * freq;
        float pe = 0.7310585786300049f * ((oc & 1) ? __cosf(a) : __sinf(a));
        v = co[(size_t)(b*25+pos)*256 + oc] + pe;
    }
    emb[(size_t)t*256 + oc] = f2bf(v);
}

// ---------------------------------------------------------------------------
// bf16 MFMA GEMM: C[M,N] = op(A[M,K] @ B + bias)*alpha [+res],  B given as Bt[N,K].
// 128x128 tile, BK=64, 256 threads (4 waves, 2x2), XOR-swizzled LDS.
template<int RESMODE, int RELU, int OUTBF>
__global__ void mfma_gemm(const u16* __restrict__ A, const u16* __restrict__ Bt,
                          const float* __restrict__ bias, const float* __restrict__ res,
                          void* __restrict__ Cout, int M, int N, int K, float alpha) {
    __shared__ u16 As[128*64];
    __shared__ u16 Bs[128*64];
    const int tid = threadIdx.x;
    const int lane = tid & 63;
    const int w = tid >> 6;
    const int wr = (w >> 1) * 64, wc = (w & 1) * 64;
    const int bm = blockIdx.y * 128, bn = blockIdx.x * 128;

    floatx4 acc[4][4];
    #pragma unroll
    for (int mi = 0; mi < 4; ++mi)
        #pragma unroll
        for (int ni = 0; ni < 4; ++ni)
            acc[mi][ni] = (floatx4){0.f,0.f,0.f,0.f};

    for (int k0 = 0; k0 < K; k0 += 64) {
        short8_t ar[4], br[4];
        #pragma unroll
        for (int s = 0; s < 4; ++s) {
            int ci = s*256 + tid;
            int row = ci >> 3, ch = ci & 7;
            ar[s] = *(const short8_t*)&A [(size_t)(bm+row)*K + k0 + ch*8];
            br[s] = *(const short8_t*)&Bt[(size_t)(bn+row)*K + k0 + ch*8];
        }
        __syncthreads();
        #pragma unroll
        for (int s = 0; s < 4; ++s) {
            int ci = s*256 + tid;
            int row = ci >> 3, ch = ci & 7;
            int off = row*64 + ((ch ^ (row & 7)) * 8);
            *(short8_t*)&As[off] = ar[s];
            *(short8_t*)&Bs[off] = br[s];
        }
        __syncthreads();
        #pragma unroll
        for (int kk = 0; kk < 2; ++kk) {
            short8_t af[4], bfr[4];
            #pragma unroll
            for (int mi = 0; mi < 4; ++mi) {
                int row = wr + mi*16 + (lane & 15);
                int ch = kk*4 + (lane >> 4);
                af[mi] = *(const short8_t*)&As[row*64 + ((ch ^ (row & 7))*8)];
            }
            #pragma unroll
            for (int ni = 0; ni < 4; ++ni) {
                int rowb = wc + ni*16 + (lane & 15);
                int ch = kk*4 + (lane >> 4);
                bfr[ni] = *(const short8_t*)&Bs[rowb*64 + ((ch ^ (rowb & 7))*8)];
            }
            #pragma unroll
            for (int mi = 0; mi < 4; ++mi)
                #pragma unroll
                for (int ni = 0; ni < 4; ++ni)
                    acc[mi][ni] = __builtin_amdgcn_mfma_f32_16x16x32_bf16(
                        af[mi], bfr[ni], acc[mi][ni], 0, 0, 0);
        }
        __syncthreads();
    }

    #pragma unroll
    for (int mi = 0; mi < 4; ++mi) {
        #pragma unroll
        for (int ni = 0; ni < 4; ++ni) {
            int col = bn + wc + ni*16 + (lane & 15);
            float bv = bias ? bias[col] : 0.0f;
            #pragma unroll
            for (int r = 0; r < 4; ++r) {
                int row = bm + wr + mi*16 + (lane >> 4)*4 + r;
                float v = (acc[mi][ni][r] + bv) * alpha;
                if (RELU) v = fmaxf(v, 0.f);
                if (RESMODE == 1)      v += res[(size_t)row*N + col];
                else if (RESMODE == 2) v += res[(size_t)(row/SEQ)*N + col];
                if (OUTBF) ((u16*)Cout)[(size_t)row*N + col] = f2bf(v);
                else       ((float*)Cout)[(size_t)row*N + col] = v;
            }
        }
    }
}

// ---------------------------------------------------------------------------
// per-batch question path
__global__ void que_map_kernel(const float* __restrict__ qst,
                               const float* __restrict__ qrep_w,
                               const float* __restrict__ qrep_b,
                               const float* __restrict__ map_w,
                               const float* __restrict__ map_b,
                               float* __restrict__ quem) {
    int b = blockIdx.x;
    int t = threadIdx.x;
    __shared__ float que[256];
    float acc = qrep_b[t];
    for (int j = 0; j < 18; ++j) acc += qst[b*18 + j] * qrep_w[j*256 + t];
    que[t] = acc;
    __syncthreads();
    for (int n = t; n < DIM; n += 256) {
        float a2 = map_b[n];
        for (int k = 0; k < 256; ++k) a2 += que[k] * map_w[(256 + k)*DIM + n];
        quem[b*DIM + n] = a2;
    }
}

// ---------------------------------------------------------------------------
// LayerNorm over D=512, bf16 out; grid TOK, block 256
__global__ void ln_kernel(const float* __restrict__ x, const float* __restrict__ g,
                          const float* __restrict__ bta, u16* __restrict__ out) {
    int t = blockIdx.x;
    int tid = threadIdx.x;
    const float* xr = x + (size_t)t*DIM;
    float v0 = xr[tid], v1 = xr[tid+256];
    float s = v0 + v1, sq = v0*v0 + v1*v1;
    __shared__ float rs[4], rq[4];
    for (int off = 32; off; off >>= 1) { s += __shfl_down(s, off); sq += __shfl_down(sq, off); }
    int wid = tid >> 6, lane = tid & 63;
    if (lane == 0) { rs[wid] = s; rq[wid] = sq; }
    __syncthreads();
    __shared__ float mean_s, rstd_s;
    if (tid == 0) {
        float ts = rs[0]+rs[1]+rs[2]+rs[3], tq = rq[0]+rq[1]+rq[2]+rq[3];
        float m = ts / DIM;
        float var = tq / DIM - m*m;
        mean_s = m; rstd_s = rsqrtf(var + 1e-5f);
    }
    __syncthreads();
    float m = mean_s, r = rstd_s;
    out[(size_t)t*DIM + tid]       = f2bf((v0 - m)*r*g[tid]     + bta[tid]);
    out[(size_t)t*DIM + tid + 256] = f2bf((v1 - m)*r*g[tid+256] + bta[tid+256]);
}

// ---------------------------------------------------------------------------
// score = softmax_k(q.k /8), qkv is bf16 [tok][1536]. Output stride 28, pads zeroed.
__global__ void score_kernel(const u16* __restrict__ qkv, float* __restrict__ score) {
    int h = blockIdx.x, b = blockIdx.y;
    __shared__ float qs[SEQ*64], ks[SEQ*64], st[SEQ*SEQ];
    int tid = threadIdx.x;
    for (int idx = tid; idx < SEQ*64; idx += 256) {
        int s_ = idx >> 6, d = idx & 63;
        qs[idx] = bf2f(qkv[(size_t)(b*SEQ+s_)*1536 + h*64 + d]) * 0.125f;
        ks[idx] = bf2f(qkv[(size_t)(b*SEQ+s_)*1536 + 512 + h*64 + d]);
    }
    __syncthreads();
    for (int idx = tid; idx < SEQ*SEQ; idx += 256) {
        int qi = idx / SEQ, ki = idx % SEQ;
        float acc = 0.0f;
        #pragma unroll
        for (int d = 0; d < 64; ++d) acc += qs[qi*64+d]*ks[ki*64+d];
        st[idx] = acc;
    }
    __syncthreads();
    if (tid < SEQ) {
        float m = -1e30f;
        for (int j = 0; j < SEQ; ++j) m = fmaxf(m, st[tid*SEQ+j]);
        float den = 0.0f;
        for (int j = 0; j < SEQ; ++j) den += __expf(st[tid*SEQ+j]-m);
        float inv = 1.0f/den;
        float* orow = score + ((size_t)(b*8+h)*SEQ + tid)*28;
        for (int j = 0; j < SEQ; ++j) orow[j] = __expf(st[tid*SEQ+j]-m)*inv;
        orow[26] = 0.f; orow[27] = 0.f;
    }
}

// ---------------------------------------------------------------------------
// Fused attention stage 2 per batch b:
//   vw[k,r]   = sum_d2 V[k, r*64+d2] * sw[d2]
//   e[h,q,r]  = sum_k s[h,q,k] * vw[k,r];  comp = softmax_r(e)
//   o[(h,q),d2] = sum_{kr} (s[h,q,k]*comp[h,q,r]) * Vflat[kr, d2]   (MFMA, K=208 pad 224)
// A-fragments (s*comp) built in registers; V staged bf16 [d2][kr] XOR-swizzled.
__global__ __launch_bounds__(512) void attn2_kernel(const u16* __restrict__ qkv,
                                                    const float* __restrict__ score,
                                                    const float* __restrict__ score_w,
                                                    u16* __restrict__ attn_o) {
    int b = blockIdx.x;
    __shared__ u16 Bt[64*224];        // [d2][kr], byte ^= (d2&7)<<4
    __shared__ float s_lds[208*28];   // [(h*26+q)][k], k 26..27 = 0
    __shared__ float vwl[208];        // [k*8+r]
    __shared__ float cmp_lds[208*8];  // [(h,q)][r]
    __shared__ float swl[64];
    int tid = threadIdx.x;

    if (tid < 64) swl[tid] = score_w[32 + tid];
    for (int idx = tid; idx < 208*28; idx += 512)
        s_lds[idx] = score[(size_t)b*5824 + idx];
    // V -> Bt (transpose to [d2][kr]); coalesced global bf16 reads
    for (int k = 0; k < 26; ++k) {
        int d2 = tid & 63, r = tid >> 6;
        u16 v = qkv[(size_t)(b*SEQ+k)*1536 + 1024 + tid];
        int bo = (d2*448 + (k*8+r)*2) ^ ((d2 & 7) << 4);
        *(u16*)((char*)Bt + bo) = v;
    }
    {   // zero-pad kr 208..223
        int d2 = tid & 63, kr = 208 + (tid >> 6);
        int bo1 = (d2*448 + kr*2)     ^ ((d2 & 7) << 4);
        int bo2 = (d2*448 + (kr+8)*2) ^ ((d2 & 7) << 4);
        *(u16*)((char*)Bt + bo1) = 0;
        *(u16*)((char*)Bt + bo2) = 0;
    }
    __syncthreads();

    if (tid < 208) {   // vw
        float acc = 0.f;
        for (int d2 = 0; d2 < 64; ++d2) {
            int bo = (d2*448 + tid*2) ^ ((d2 & 7) << 4);
            acc += bf2f(*(const u16*)((const char*)Bt + bo)) * swl[d2];
        }
        vwl[tid] = acc;
    }
    __syncthreads();

    if (tid < 208) {   // e + softmax over r
        float srow[26];
        #pragma unroll
        for (int k = 0; k < 26; ++k) srow[k] = s_lds[tid*28 + k];
        float e[8];
        #pragma unroll
        for (int r = 0; r < 8; ++r) {
            float a = 0.f;
            #pragma unroll
            for (int k = 0; k < 26; ++k) a += srow[k] * vwl[k*8 + r];
            e[r] = a;
        }
        float m = e[0];
        #pragma unroll
        for (int r = 1; r < 8; ++r) m = fmaxf(m, e[r]);
        float den = 0.f;
        #pragma unroll
        for (int r = 0; r < 8; ++r) { e[r] = __expf(e[r]-m); den += e[r]; }
        float inv = 1.f/den;
        #pragma unroll
        for (int r = 0; r < 8; ++r) cmp_lds[tid*8+r] = e[r]*inv;
    }
    __syncthreads();

    // MFMA: C[208][64] = w2[208][224] @ Vflat[224][64]
    int lane = tid & 63, w = tid >> 6;
    int mh = w >> 2, nt = w & 3;
    int ntile0 = nt*16;
    short8_t bfr[7];
    #pragma unroll
    for (int ks = 0; ks < 7; ++ks) {
        int col = ntile0 + (lane & 15);
        int krb = ks*32 + (lane >> 4)*8;
        int bo = (col*448 + krb*2) ^ ((col & 7) << 4);
        bfr[ks] = *(const short8_t*)((const char*)Bt + bo);
    }
    int mt0 = mh ? 7 : 0, mt1 = mh ? 13 : 7;
    for (int mt = mt0; mt < mt1; ++mt) {
        int arow = mt*16 + (lane & 15);
        float c8[8];
        #pragma unroll
        for (int r = 0; r < 8; ++r) c8[r] = cmp_lds[arow*8 + r];
        floatx4 acc = (floatx4){0.f,0.f,0.f,0.f};
        #pragma unroll
        for (int ks = 0; ks < 7; ++ks) {
            int k = ks*4 + (lane >> 4);
            float sv = s_lds[arow*28 + k];
            short8_t af;
            #pragma unroll
            for (int j = 0; j < 8; ++j) af[j] = (short)f2bf(sv * c8[j]);
            acc = __builtin_amdgcn_mfma_f32_16x16x32_bf16(af, bfr[ks], acc, 0, 0, 0);
        }
        int colg = ntile0 + (lane & 15);
        #pragma unroll
        for (int rr = 0; rr < 4; ++rr) {
            int rowg = mt*16 + (lane >> 4)*4 + rr;
            int h = rowg / 26, q = rowg - h*26;
            attn_o[(size_t)(b*SEQ+q)*DIM + h*64 + colg] = f2bf(acc[rr]);
        }
    }
}

// ---------------------------------------------------------------------------
__global__ void head_kernel(const float* __restrict__ x, const float* __restrict__ out_w,
                            const float* __restrict__ out_b, float* __restrict__ y) {
    int b = blockIdx.x;
    int t = threadIdx.x;
    __shared__ float yv[10];
    if (t < 10) {
        float acc = out_b[t];
        const float* xr = x + (size_t)(b*SEQ)*DIM;
        for (int dd = 0; dd < DIM; ++dd) acc += xr[dd]*out_w[dd*10 + t];
        yv[t] = acc;
    }
    __syncthreads();
    if (t < 10) {
        float m = yv[0];
        for (int i = 1; i < 10; ++i) m = fmaxf(m, yv[i]);
        float den = 0.0f;
        for (int i = 0; i < 10; ++i) den += expf(yv[i]-m);
        y[b*10 + t] = yv[t] - m - logf(den);
    }
}

// ---------------------------------------------------------------------------
extern "C" void kernel_launch(void* const* d_in, const int* in_sizes, int n_in,
                              void* d_out, int out_size, void* d_ws, size_t ws_size,
                              hipStream_t stream) {
    const float* img      = (const float*)d_in[0];
    const float* qst      = (const float*)d_in[1];
    const float* conv_w   = (const float*)d_in[2];
    const float* conv_b   = (const float*)d_in[3];
    const float* qrep_w   = (const float*)d_in[4];
    const float* qrep_b   = (const float*)d_in[5];
    const float* cls_tok  = (const float*)d_in[6];
    const float* map_w    = (const float*)d_in[7];
    const float* map_b    = (const float*)d_in[8];
    const float* norm1_g  = (const float*)d_in[9];
    const float* norm1_b  = (const float*)d_in[10];
    const float* norm2_g  = (const float*)d_in[11];
    const float* norm2_b  = (const float*)d_in[12];
    const float* q_w      = (const float*)d_in[13];
    const float* q_b      = (const float*)d_in[14];
    const float* k_w      = (const float*)d_in[15];
    const float* k_b      = (const float*)d_in[16];
    const float* v_w      = (const float*)d_in[17];
    const float* v_b      = (const float*)d_in[18];
    // d_in[19] qv_w, d_in[20] qv_b: cancel in r-softmax — unused
    const float* score_w  = (const float*)d_in[21];
    // d_in[22] score_b: constant along softmax axis — unused
    const float* final_w  = (const float*)d_in[23];
    const float* final_b  = (const float*)d_in[24];
    const float* ffn1_w   = (const float*)d_in[25];
    const float* ffn1_b   = (const float*)d_in[26];
    const float* ffn2_w   = (const float*)d_in[27];
    const float* ffn2_b   = (const float*)d_in[28];
    const float* out_w    = (const float*)d_in[29];
    const float* out_b    = (const float*)d_in[30];

    float* ws = (float*)d_ws;
    size_t o = 0;
    float* x    = ws + o;       o += (size_t)TOK*DIM;
    u16* qkvT   = (u16*)(ws+o); o += (size_t)1536*512/2;
    u16* finT   = (u16*)(ws+o); o += (size_t)512*512/2;
    u16* f1T    = (u16*)(ws+o); o += (size_t)1024*512/2;
    u16* f2T    = (u16*)(ws+o); o += (size_t)512*1024/2;
    u16* mapT   = (u16*)(ws+o); o += (size_t)512*256/2;
    u16* cwT    = (u16*)(ws+o); o += (size_t)256*704/2;
    float* qkvb = ws + o;       o += 1536;
    float* r2   = ws + o;
    // phase-2 layout in r2
    u16*  h_bf    = (u16*)r2;                                  // TOK*512 bf16
    u16*  qkv_bf  = (u16*)(r2 + (size_t)TOK*DIM/2);            // TOK*1536 bf16
    float* scoreb = r2 + (size_t)TOK*DIM/2 + (size_t)TOK*1536/2; // NB*8*26*28 f32
    u16*  attn_obf= (u16*)(scoreb + (size_t)NB*8*SEQ*28);      // TOK*512 bf16
    u16*  ffbuf   = qkv_bf;                                    // alias (qkv dead in FFN)
    // phase-1 aliases r2
    u16*  Pbuf    = (u16*)r2;                                  // 6400*704 bf16
    float* convout= r2 + (size_t)6400*704/2;
    u16*  emb_bf  = (u16*)(convout + (size_t)6400*256);
    float* quem   = convout + (size_t)6400*256 + (size_t)TOK*256/2;

    // ---- weight conversion (bf16, [N][K]) ----
    wtrans<<<512, 256, 0, stream>>>(q_w,     qkvT,              512, 512);
    wtrans<<<512, 256, 0, stream>>>(k_w,     qkvT + 512*512,    512, 512);
    wtrans<<<512, 256, 0, stream>>>(v_w,     qkvT + 1024*512,   512, 512);
    wtrans<<<512, 256, 0, stream>>>(final_w, finT,              512, 512);
    wtrans<<<1024,256, 0, stream>>>(ffn1_w,  f1T,               512, 1024);
    wtrans<<<512, 256, 0, stream>>>(ffn2_w,  f2T,               1024, 512);
    wtrans<<<512, 256, 0, stream>>>(map_w,   mapT,              256, 512);
    convw_bf<<<256, 256, 0, stream>>>(conv_w, cwT);
    concat3<<<6, 256, 0, stream>>>(q_b, k_b, v_b, qkvb);

    // ---- phase 1: embedding ----
    im2col_kernel<<<6400, 256, 0, stream>>>(img, Pbuf);
    que_map_kernel<<<NB, 256, 0, stream>>>(qst, qrep_w, qrep_b, map_w, map_b, quem);
    mfma_gemm<0,0,0><<<dim3(2,50), dim3(256), 0, stream>>>(
        Pbuf, cwT, conv_b, nullptr, convout, 6400, 256, 704, 1.0f);
    pe_cls_kernel<<<TOK, 256, 0, stream>>>(convout, cls_tok, emb_bf);
    mfma_gemm<2,0,0><<<dim3(4,52), dim3(256), 0, stream>>>(
        emb_bf, mapT, nullptr, quem, x, TOK, 512, 256, 1.0f);

    // ---- phase 2: 4 transformer iterations ----
    for (int it = 0; it < 4; ++it) {
        ln_kernel<<<TOK, 256, 0, stream>>>(x, norm1_g, norm1_b, h_bf);
        mfma_gemm<0,0,1><<<dim3(12,52), dim3(256), 0, stream>>>(
            h_bf, qkvT, qkvb, nullptr, qkv_bf, TOK, 1536, 512, 1.0f);
        score_kernel<<<dim3(8,NB), 256, 0, stream>>>(qkv_bf, scoreb);
        attn2_kernel<<<NB, 512, 0, stream>>>(qkv_bf, scoreb, score_w, attn_obf);
        mfma_gemm<1,0,0><<<dim3(4,52), dim3(256), 0, stream>>>(
            attn_obf, finT, final_b, x, x, TOK, 512, 512, 1.0f);
        ln_kernel<<<TOK, 256, 0, stream>>>(x, norm2_g, norm2_b, h_bf);
        mfma_gemm<0,1,1><<<dim3(8,52), dim3(256), 0, stream>>>(
            h_bf, f1T, ffn1_b, nullptr, ffbuf, TOK, 1024, 512, 1.0f);
        mfma_gemm<1,0,0><<<dim3(4,52), dim3(256), 0, stream>>>(
            ffbuf, f2T, ffn2_b, x, x, TOK, 512, 1024, 1.0f);
    }

    head_kernel<<<NB, 64, 0, stream>>>(x, out_w, out_b, (float*)d_out);
}

// Round 4
// 670.926 us; speedup vs baseline: 7.2085x; 1.2364x over previous
//
#include <hip/hip_runtime.h>
#include <math.h>

#define NB 256
#define SEQ 26
#define TOK (NB*SEQ)   // 6656
#define DIM 512

typedef unsigned short u16;
typedef __attribute__((ext_vector_type(8))) short short8_t;
typedef __attribute__((ext_vector_type(4))) float floatx4;

__device__ inline u16 f2bf(float f) {
    union { float f; unsigned u; } v; v.f = f;
    unsigned r = v.u + 0x7fffu + ((v.u >> 16) & 1u);
    return (u16)(r >> 16);
}
__device__ inline float bf2f(u16 u) {
    union { unsigned u; float f; } v; v.u = ((unsigned)u) << 16; return v.f;
}

// ---------------------------------------------------------------------------
// Weight transpose+convert: Wt[n*K + k] = bf16(W[k*N + n]).  grid N, block 256.
__global__ void wtrans(const float* __restrict__ W, u16* __restrict__ Wt, int K, int N) {
    int n = blockIdx.x;
    for (int k = threadIdx.x; k < K; k += 256)
        Wt[(size_t)n*K + k] = f2bf(W[(size_t)k*N + n]);
}

// conv_w [256][675] -> bf16 [256][704] zero-padded (already [N][K] layout)
__global__ void convw_bf(const float* __restrict__ W, u16* __restrict__ Wb) {
    int oc = blockIdx.x;
    for (int j = threadIdx.x; j < 704; j += 256)
        Wb[(size_t)oc*704 + j] = (j < 675) ? f2bf(W[(size_t)oc*675 + j]) : (u16)0;
}

__global__ void concat3(const float* __restrict__ a, const float* __restrict__ b,
                        const float* __restrict__ c, float* __restrict__ o) {
    int t = blockIdx.x*256 + threadIdx.x;  // 0..1535
    o[t] = t < 512 ? a[t] : (t < 1024 ? b[t-512] : c[t-1024]);
}

// ---------------------------------------------------------------------------
// im2col: P[(b*25+pos)][j] bf16, K padded to 704
__global__ void im2col_kernel(const float* __restrict__ img, u16* __restrict__ P) {
    int ri = blockIdx.x;               // 0..6399
    int b = ri / 25, pos = ri % 25, ph = pos/5, pw = pos%5;
    for (int j = threadIdx.x; j < 704; j += 256) {
        float v = 0.f;
        if (j < 675) {
            int c = j / 225, rem = j % 225, kh = rem/15, kw = rem%15;
            v = img[(size_t)((b*3+c)*75 + ph*15 + kh)*75 + pw*15 + kw];
        }
        P[(size_t)ri*704 + j] = f2bf(v);
    }
}

// emb rows: cls row + (convout + pe) rows, bf16
__global__ void pe_cls_kernel(const float* __restrict__ co, const float* __restrict__ cls,
                              u16* __restrict__ emb) {
    int t = blockIdx.x;                // 0..6655
    int b = t / SEQ, s = t % SEQ;
    int oc = threadIdx.x;              // 0..255
    float v;
    if (s == 0) v = cls[oc];
    else {
        int pos = s - 1;
        float freq = __powf(10000.0f, -(float)oc / 128.0f);
        float a = (float)pos * freq;
        float pe = 0.7310585786300049f * ((oc & 1) ? __cosf(a) : __sinf(a));
        v = co[(size_t)(b*25+pos)*256 + oc] + pe;
    }
    emb[(size_t)t*256 + oc] = f2bf(v);
}

// ---------------------------------------------------------------------------
// bf16 MFMA GEMM: C[M,N] = op(A[M,K] @ B + bias)*alpha [+res],  B given as Bt[N,K].
// 128x128 tile, BK=64, 256 threads (4 waves, 2x2), XOR-swizzled LDS.
template<int RESMODE, int RELU, int OUTBF>
__global__ void mfma_gemm(const u16* __restrict__ A, const u16* __restrict__ Bt,
                          const float* __restrict__ bias, const float* __restrict__ res,
                          void* __restrict__ Cout, int M, int N, int K, float alpha) {
    __shared__ u16 As[128*64];
    __shared__ u16 Bs[128*64];
    const int tid = threadIdx.x;
    const int lane = tid & 63;
    const int w = tid >> 6;
    const int wr = (w >> 1) * 64, wc = (w & 1) * 64;
    const int bm = blockIdx.y * 128, bn = blockIdx.x * 128;

    floatx4 acc[4][4];
    #pragma unroll
    for (int mi = 0; mi < 4; ++mi)
        #pragma unroll
        for (int ni = 0; ni < 4; ++ni)
            acc[mi][ni] = (floatx4){0.f,0.f,0.f,0.f};

    for (int k0 = 0; k0 < K; k0 += 64) {
        short8_t ar[4], br[4];
        #pragma unroll
        for (int s = 0; s < 4; ++s) {
            int ci = s*256 + tid;
            int row = ci >> 3, ch = ci & 7;
            ar[s] = *(const short8_t*)&A [(size_t)(bm+row)*K + k0 + ch*8];
            br[s] = *(const short8_t*)&Bt[(size_t)(bn+row)*K + k0 + ch*8];
        }
        __syncthreads();
        #pragma unroll
        for (int s = 0; s < 4; ++s) {
            int ci = s*256 + tid;
            int row = ci >> 3, ch = ci & 7;
            int off = row*64 + ((ch ^ (row & 7)) * 8);
            *(short8_t*)&As[off] = ar[s];
            *(short8_t*)&Bs[off] = br[s];
        }
        __syncthreads();
        #pragma unroll
        for (int kk = 0; kk < 2; ++kk) {
            short8_t af[4], bfr[4];
            #pragma unroll
            for (int mi = 0; mi < 4; ++mi) {
                int row = wr + mi*16 + (lane & 15);
                int ch = kk*4 + (lane >> 4);
                af[mi] = *(const short8_t*)&As[row*64 + ((ch ^ (row & 7))*8)];
            }
            #pragma unroll
            for (int ni = 0; ni < 4; ++ni) {
                int rowb = wc + ni*16 + (lane & 15);
                int ch = kk*4 + (lane >> 4);
                bfr[ni] = *(const short8_t*)&Bs[rowb*64 + ((ch ^ (rowb & 7))*8)];
            }
            #pragma unroll
            for (int mi = 0; mi < 4; ++mi)
                #pragma unroll
                for (int ni = 0; ni < 4; ++ni)
                    acc[mi][ni] = __builtin_amdgcn_mfma_f32_16x16x32_bf16(
                        af[mi], bfr[ni], acc[mi][ni], 0, 0, 0);
        }
        __syncthreads();
    }

    #pragma unroll
    for (int mi = 0; mi < 4; ++mi) {
        #pragma unroll
        for (int ni = 0; ni < 4; ++ni) {
            int col = bn + wc + ni*16 + (lane & 15);
            float bv = bias ? bias[col] : 0.0f;
            #pragma unroll
            for (int r = 0; r < 4; ++r) {
                int row = bm + wr + mi*16 + (lane >> 4)*4 + r;
                float v = (acc[mi][ni][r] + bv) * alpha;
                if (RELU) v = fmaxf(v, 0.f);
                if (RESMODE == 1)      v += res[(size_t)row*N + col];
                else if (RESMODE == 2) v += res[(size_t)(row/SEQ)*N + col];
                if (OUTBF) ((u16*)Cout)[(size_t)row*N + col] = f2bf(v);
                else       ((float*)Cout)[(size_t)row*N + col] = v;
            }
        }
    }
}

// ---------------------------------------------------------------------------
// per-batch question path
__global__ void que_map_kernel(const float* __restrict__ qst,
                               const float* __restrict__ qrep_w,
                               const float* __restrict__ qrep_b,
                               const float* __restrict__ map_w,
                               const float* __restrict__ map_b,
                               float* __restrict__ quem) {
    int b = blockIdx.x;
    int t = threadIdx.x;
    __shared__ float que[256];
    float acc = qrep_b[t];
    for (int j = 0; j < 18; ++j) acc += qst[b*18 + j] * qrep_w[j*256 + t];
    que[t] = acc;
    __syncthreads();
    for (int n = t; n < DIM; n += 256) {
        float a2 = map_b[n];
        for (int k = 0; k < 256; ++k) a2 += que[k] * map_w[(256 + k)*DIM + n];
        quem[b*DIM + n] = a2;
    }
}

// ---------------------------------------------------------------------------
// LayerNorm over D=512, bf16 out; grid TOK, block 256
__global__ void ln_kernel(const float* __restrict__ x, const float* __restrict__ g,
                          const float* __restrict__ bta, u16* __restrict__ out) {
    int t = blockIdx.x;
    int tid = threadIdx.x;
    const float* xr = x + (size_t)t*DIM;
    float v0 = xr[tid], v1 = xr[tid+256];
    float s = v0 + v1, sq = v0*v0 + v1*v1;
    __shared__ float rs[4], rq[4];
    for (int off = 32; off; off >>= 1) { s += __shfl_down(s, off); sq += __shfl_down(sq, off); }
    int wid = tid >> 6, lane = tid & 63;
    if (lane == 0) { rs[wid] = s; rq[wid] = sq; }
    __syncthreads();
    __shared__ float mean_s, rstd_s;
    if (tid == 0) {
        float ts = rs[0]+rs[1]+rs[2]+rs[3], tq = rq[0]+rq[1]+rq[2]+rq[3];
        float m = ts / DIM;
        float var = tq / DIM - m*m;
        mean_s = m; rstd_s = rsqrtf(var + 1e-5f);
    }
    __syncthreads();
    float m = mean_s, r = rstd_s;
    out[(size_t)t*DIM + tid]       = f2bf((v0 - m)*r*g[tid]     + bta[tid]);
    out[(size_t)t*DIM + tid + 256] = f2bf((v1 - m)*r*g[tid+256] + bta[tid+256]);
}

// ---------------------------------------------------------------------------
// Fully fused attention per batch b (512 threads = 8 waves):
//  (a) wave h computes S_h = softmax_k(Q_h K_h^T / 8) via MFMA -> s_lds [208][28]
//  (b) vw[k,r] = sum_d2 V[k,r*64+d2]*sw[d2]
//  (c) e[hq,r] = sum_k s*vw; comp = softmax_r(e)   (qv & score_b cancel)
//  (d) o[(h,q),d2] = sum_kr (s*comp) @ Vflat  via MFMA (K=208 pad 224)
__global__ __launch_bounds__(512) void attn_fused_kernel(const u16* __restrict__ qkv,
                                                         const float* __restrict__ score_w,
                                                         u16* __restrict__ attn_o) {
    int b = blockIdx.x;
    __shared__ u16 Bt[64*224];        // V as [d2][kr], byte ^= (d2&7)<<4
    __shared__ float s_lds[208*28];   // [(h*26+q)][k], k 26..27 = 0
    __shared__ float vwl[208];        // [k*8+r]
    __shared__ float cmp_lds[208*8];  // [(h,q)][r]
    __shared__ float swl[64];
    int tid = threadIdx.x;
    int lane = tid & 63, w = tid >> 6;

    if (tid < 64) swl[tid] = score_w[32 + tid];
    // V -> Bt (transpose to [d2][kr]); coalesced global bf16 reads
    for (int k = 0; k < 26; ++k) {
        int d2 = tid & 63, r = tid >> 6;
        u16 v = qkv[(size_t)(b*SEQ+k)*1536 + 1024 + tid];
        int bo = (d2*448 + (k*8+r)*2) ^ ((d2 & 7) << 4);
        *(u16*)((char*)Bt + bo) = v;
    }
    {   // zero-pad kr 208..223
        int d2 = tid & 63, kr = 208 + (tid >> 6);
        int bo1 = (d2*448 + kr*2)     ^ ((d2 & 7) << 4);
        int bo2 = (d2*448 + (kr+8)*2) ^ ((d2 & 7) << 4);
        *(u16*)((char*)Bt + bo1) = 0;
        *(u16*)((char*)Bt + bo2) = 0;
    }
    // zero-pad s_lds cols 26,27
    for (int row = tid; row < 208; row += 512) {
        s_lds[row*28 + 26] = 0.f; s_lds[row*28 + 27] = 0.f;
    }

    // ---- (a) QK^T + softmax, wave w handles head h=w ----
    {
        int h = w;
        int col16 = lane & 15, ch = lane >> 4;   // ch = k-chunk / row-group
        short8_t qf[2][2], kf[2][2];
        #pragma unroll
        for (int mi = 0; mi < 2; ++mi) {
            int q = mi*16 + col16;
            #pragma unroll
            for (int kk = 0; kk < 2; ++kk) {
                if (q < 26)
                    qf[mi][kk] = *(const short8_t*)&qkv[(size_t)(b*SEQ+q)*1536 + h*64 + kk*32 + ch*8];
                else
                    qf[mi][kk] = (short8_t){0,0,0,0,0,0,0,0};
            }
        }
        #pragma unroll
        for (int ni = 0; ni < 2; ++ni) {
            int kq = ni*16 + col16;
            #pragma unroll
            for (int kk = 0; kk < 2; ++kk) {
                if (kq < 26)
                    kf[ni][kk] = *(const short8_t*)&qkv[(size_t)(b*SEQ+kq)*1536 + 512 + h*64 + kk*32 + ch*8];
                else
                    kf[ni][kk] = (short8_t){0,0,0,0,0,0,0,0};
            }
        }
        floatx4 sacc[2][2];
        #pragma unroll
        for (int mi = 0; mi < 2; ++mi)
            #pragma unroll
            for (int ni = 0; ni < 2; ++ni)
                sacc[mi][ni] = (floatx4){0.f,0.f,0.f,0.f};
        #pragma unroll
        for (int kk = 0; kk < 2; ++kk)
            #pragma unroll
            for (int mi = 0; mi < 2; ++mi)
                #pragma unroll
                for (int ni = 0; ni < 2; ++ni)
                    sacc[mi][ni] = __builtin_amdgcn_mfma_f32_16x16x32_bf16(
                        qf[mi][kk], kf[ni][kk], sacc[mi][ni], 0, 0, 0);
        // row softmax: row q = mi*16 + ch*4 + r lives in the 16 lanes of this ch-group
        #pragma unroll
        for (int mi = 0; mi < 2; ++mi) {
            #pragma unroll
            for (int r = 0; r < 4; ++r) {
                float s0 = sacc[mi][0][r] * 0.125f;
                float s1 = (col16 < 10) ? sacc[mi][1][r] * 0.125f : -1e30f;
                float mx = fmaxf(s0, s1);
                #pragma unroll
                for (int msk = 1; msk < 16; msk <<= 1) mx = fmaxf(mx, __shfl_xor(mx, msk));
                float e0 = __expf(s0 - mx);
                float e1 = (col16 < 10) ? __expf(s1 - mx) : 0.f;
                float den = e0 + e1;
                #pragma unroll
                for (int msk = 1; msk < 16; msk <<= 1) den += __shfl_xor(den, msk);
                float inv = 1.f / den;
                int q = mi*16 + ch*4 + r;
                if (q < 26) {
                    s_lds[(h*26+q)*28 + col16] = e0 * inv;
                    if (col16 < 10) s_lds[(h*26+q)*28 + 16 + col16] = e1 * inv;
                }
            }
        }
    }
    __syncthreads();

    // ---- (b) vw ----
    if (tid < 208) {
        float acc = 0.f;
        for (int d2 = 0; d2 < 64; ++d2) {
            int bo = (d2*448 + tid*2) ^ ((d2 & 7) << 4);
            acc += bf2f(*(const u16*)((const char*)Bt + bo)) * swl[d2];
        }
        vwl[tid] = acc;
    }
    __syncthreads();

    // ---- (c) e + softmax over r ----
    if (tid < 208) {
        float srow[26];
        #pragma unroll
        for (int k = 0; k < 26; ++k) srow[k] = s_lds[tid*28 + k];
        float e[8];
        #pragma unroll
        for (int r = 0; r < 8; ++r) {
            float a = 0.f;
            #pragma unroll
            for (int k = 0; k < 26; ++k) a += srow[k] * vwl[k*8 + r];
            e[r] = a;
        }
        float m = e[0];
        #pragma unroll
        for (int r = 1; r < 8; ++r) m = fmaxf(m, e[r]);
        float den = 0.f;
        #pragma unroll
        for (int r = 0; r < 8; ++r) { e[r] = __expf(e[r]-m); den += e[r]; }
        float inv = 1.f/den;
        #pragma unroll
        for (int r = 0; r < 8; ++r) cmp_lds[tid*8+r] = e[r]*inv;
    }
    __syncthreads();

    // ---- (d) MFMA: C[208][64] = w2[208][224] @ Vflat[224][64] ----
    int mh = w >> 2, nt = w & 3;
    int ntile0 = nt*16;
    short8_t bfr[7];
    #pragma unroll
    for (int ks = 0; ks < 7; ++ks) {
        int col = ntile0 + (lane & 15);
        int krb = ks*32 + (lane >> 4)*8;
        int bo = (col*448 + krb*2) ^ ((col & 7) << 4);
        bfr[ks] = *(const short8_t*)((const char*)Bt + bo);
    }
    int mt0 = mh ? 7 : 0, mt1 = mh ? 13 : 7;
    for (int mt = mt0; mt < mt1; ++mt) {
        int arow = mt*16 + (lane & 15);
        float c8[8];
        #pragma unroll
        for (int r = 0; r < 8; ++r) c8[r] = cmp_lds[arow*8 + r];
        floatx4 acc = (floatx4){0.f,0.f,0.f,0.f};
        #pragma unroll
        for (int ks = 0; ks < 7; ++ks) {
            int k = ks*4 + (lane >> 4);
            float sv = s_lds[arow*28 + k];
            short8_t af;
            #pragma unroll
            for (int j = 0; j < 8; ++j) af[j] = (short)f2bf(sv * c8[j]);
            acc = __builtin_amdgcn_mfma_f32_16x16x32_bf16(af, bfr[ks], acc, 0, 0, 0);
        }
        int colg = ntile0 + (lane & 15);
        #pragma unroll
        for (int rr = 0; rr < 4; ++rr) {
            int rowg = mt*16 + (lane >> 4)*4 + rr;
            int h = rowg / 26, q = rowg - h*26;
            attn_o[(size_t)(b*SEQ+q)*DIM + h*64 + colg] = f2bf(acc[rr]);
        }
    }
}

// ---------------------------------------------------------------------------
__global__ void head_kernel(const float* __restrict__ x, const float* __restrict__ out_w,
                            const float* __restrict__ out_b, float* __restrict__ y) {
    int b = blockIdx.x;
    int t = threadIdx.x;
    __shared__ float yv[10];
    if (t < 10) {
        float acc = out_b[t];
        const float* xr = x + (size_t)(b*SEQ)*DIM;
        for (int dd = 0; dd < DIM; ++dd) acc += xr[dd]*out_w[dd*10 + t];
        yv[t] = acc;
    }
    __syncthreads();
    if (t < 10) {
        float m = yv[0];
        for (int i = 1; i < 10; ++i) m = fmaxf(m, yv[i]);
        float den = 0.0f;
        for (int i = 0; i < 10; ++i) den += expf(yv[i]-m);
        y[b*10 + t] = yv[t] - m - logf(den);
    }
}

// ---------------------------------------------------------------------------
extern "C" void kernel_launch(void* const* d_in, const int* in_sizes, int n_in,
                              void* d_out, int out_size, void* d_ws, size_t ws_size,
                              hipStream_t stream) {
    const float* img      = (const float*)d_in[0];
    const float* qst      = (const float*)d_in[1];
    const float* conv_w   = (const float*)d_in[2];
    const float* conv_b   = (const float*)d_in[3];
    const float* qrep_w   = (const float*)d_in[4];
    const float* qrep_b   = (const float*)d_in[5];
    const float* cls_tok  = (const float*)d_in[6];
    const float* map_w    = (const float*)d_in[7];
    const float* map_b    = (const float*)d_in[8];
    const float* norm1_g  = (const float*)d_in[9];
    const float* norm1_b  = (const float*)d_in[10];
    const float* norm2_g  = (const float*)d_in[11];
    const float* norm2_b  = (const float*)d_in[12];
    const float* q_w      = (const float*)d_in[13];
    const float* q_b      = (const float*)d_in[14];
    const float* k_w      = (const float*)d_in[15];
    const float* k_b      = (const float*)d_in[16];
    const float* v_w      = (const float*)d_in[17];
    const float* v_b      = (const float*)d_in[18];
    // d_in[19] qv_w, d_in[20] qv_b: cancel in r-softmax — unused
    const float* score_w  = (const float*)d_in[21];
    // d_in[22] score_b: constant along softmax axis — unused
    const float* final_w  = (const float*)d_in[23];
    const float* final_b  = (const float*)d_in[24];
    const float* ffn1_w   = (const float*)d_in[25];
    const float* ffn1_b   = (const float*)d_in[26];
    const float* ffn2_w   = (const float*)d_in[27];
    const float* ffn2_b   = (const float*)d_in[28];
    const float* out_w    = (const float*)d_in[29];
    const float* out_b    = (const float*)d_in[30];

    float* ws = (float*)d_ws;
    size_t o = 0;
    float* x    = ws + o;       o += (size_t)TOK*DIM;
    u16* qkvT   = (u16*)(ws+o); o += (size_t)1536*512/2;
    u16* finT   = (u16*)(ws+o); o += (size_t)512*512/2;
    u16* f1T    = (u16*)(ws+o); o += (size_t)1024*512/2;
    u16* f2T    = (u16*)(ws+o); o += (size_t)512*1024/2;
    u16* mapT   = (u16*)(ws+o); o += (size_t)512*256/2;
    u16* cwT    = (u16*)(ws+o); o += (size_t)256*704/2;
    float* qkvb = ws + o;       o += 1536;
    float* r2   = ws + o;
    // phase-2 layout in r2
    u16*  h_bf    = (u16*)r2;                                  // TOK*512 bf16
    u16*  qkv_bf  = (u16*)(r2 + (size_t)TOK*DIM/2);            // TOK*1536 bf16
    u16*  attn_obf= (u16*)(r2 + (size_t)TOK*DIM/2 + (size_t)TOK*1536/2); // TOK*512 bf16
    u16*  ffbuf   = qkv_bf;                                    // alias (qkv dead in FFN)
    // phase-1 aliases r2
    u16*  Pbuf    = (u16*)r2;                                  // 6400*704 bf16
    float* convout= r2 + (size_t)6400*704/2;
    u16*  emb_bf  = (u16*)(convout + (size_t)6400*256);
    float* quem   = convout + (size_t)6400*256 + (size_t)TOK*256/2;

    // ---- weight conversion (bf16, [N][K]) ----
    wtrans<<<512, 256, 0, stream>>>(q_w,     qkvT,              512, 512);
    wtrans<<<512, 256, 0, stream>>>(k_w,     qkvT + 512*512,    512, 512);
    wtrans<<<512, 256, 0, stream>>>(v_w,     qkvT + 1024*512,   512, 512);
    wtrans<<<512, 256, 0, stream>>>(final_w, finT,              512, 512);
    wtrans<<<1024,256, 0, stream>>>(ffn1_w,  f1T,               512, 1024);
    wtrans<<<512, 256, 0, stream>>>(ffn2_w,  f2T,               1024, 512);
    wtrans<<<512, 256, 0, stream>>>(map_w,   mapT,              256, 512);
    convw_bf<<<256, 256, 0, stream>>>(conv_w, cwT);
    concat3<<<6, 256, 0, stream>>>(q_b, k_b, v_b, qkvb);

    // ---- phase 1: embedding ----
    im2col_kernel<<<6400, 256, 0, stream>>>(img, Pbuf);
    que_map_kernel<<<NB, 256, 0, stream>>>(qst, qrep_w, qrep_b, map_w, map_b, quem);
    mfma_gemm<0,0,0><<<dim3(2,50), dim3(256), 0, stream>>>(
        Pbuf, cwT, conv_b, nullptr, convout, 6400, 256, 704, 1.0f);
    pe_cls_kernel<<<TOK, 256, 0, stream>>>(convout, cls_tok, emb_bf);
    mfma_gemm<2,0,0><<<dim3(4,52), dim3(256), 0, stream>>>(
        emb_bf, mapT, nullptr, quem, x, TOK, 512, 256, 1.0f);

    // ---- phase 2: 4 transformer iterations ----
    for (int it = 0; it < 4; ++it) {
        ln_kernel<<<TOK, 256, 0, stream>>>(x, norm1_g, norm1_b, h_bf);
        mfma_gemm<0,0,1><<<dim3(12,52), dim3(256), 0, stream>>>(
            h_bf, qkvT, qkvb, nullptr, qkv_bf, TOK, 1536, 512, 1.0f);
        attn_fused_kernel<<<NB, 512, 0, stream>>>(qkv_bf, score_w, attn_obf);
        mfma_gemm<1,0,0><<<dim3(4,52), dim3(256), 0, stream>>>(
            attn_obf, finT, final_b, x, x, TOK, 512, 512, 1.0f);
        ln_kernel<<<TOK, 256, 0, stream>>>(x, norm2_g, norm2_b, h_bf);
        mfma_gemm<0,1,1><<<dim3(8,52), dim3(256), 0, stream>>>(
            h_bf, f1T, ffn1_b, nullptr, ffbuf, TOK, 1024, 512, 1.0f);
        mfma_gemm<1,0,0><<<dim3(4,52), dim3(256), 0, stream>>>(
            ffbuf, f2T, ffn2_b, x, x, TOK, 512, 1024, 1.0f);
    }

    head_kernel<<<NB, 64, 0, stream>>>(x, out_w, out_b, (float*)d_out);
}

// Round 6
// 620.985 us; speedup vs baseline: 7.7882x; 1.0804x over previous
//
#include <hip/hip_runtime.h>
#include <math.h>

#define NB 256
#define SEQ 26
#define TOK (NB*SEQ)   // 6656
#define DIM 512

typedef unsigned short u16;
typedef __attribute__((ext_vector_type(8))) short short8_t;
typedef __attribute__((ext_vector_type(4))) float floatx4;

__device__ inline u16 f2bf(float f) {
    union { float f; unsigned u; } v; v.f = f;
    unsigned r = v.u + 0x7fffu + ((v.u >> 16) & 1u);
    return (u16)(r >> 16);
}
__device__ inline float bf2f(u16 u) {
    union { unsigned u; float f; } v; v.u = ((unsigned)u) << 16; return v.f;
}

__device__ __forceinline__ void gload_lds16(const u16* g, u16* l) {
    __builtin_amdgcn_global_load_lds((const __attribute__((address_space(1))) void*)g,
                                     (__attribute__((address_space(3))) void*)l, 16, 0, 0);
}

// ---------------------------------------------------------------------------
// One-shot weight prep: 64x64 LDS tile transposes (f32 -> bf16 [N][K]),
// conv_w row-copy (pad 675->704), qkv bias concat.  Grid 801, block 256.
__global__ void prep_all(const float* __restrict__ q_w, const float* __restrict__ k_w,
                         const float* __restrict__ v_w, const float* __restrict__ final_w,
                         const float* __restrict__ ffn1_w, const float* __restrict__ ffn2_w,
                         const float* __restrict__ map_w, const float* __restrict__ conv_w,
                         const float* __restrict__ q_b, const float* __restrict__ k_b,
                         const float* __restrict__ v_b,
                         u16* __restrict__ qkvT, u16* __restrict__ finT,
                         u16* __restrict__ f1T, u16* __restrict__ f2T,
                         u16* __restrict__ mapT, u16* __restrict__ cwT,
                         float* __restrict__ qkvb) {
    __shared__ float lds[64][65];
    int blk = blockIdx.x;
    int t = threadIdx.x;
    if (blk < 544) {
        const float* W; u16* Wt; int K, N, tbase;
        if (blk < 64)       { W = q_w;     Wt = qkvT;            K = 512;  N = 512;  tbase = 0;   }
        else if (blk < 128) { W = k_w;     Wt = qkvT + 512*512;  K = 512;  N = 512;  tbase = 64;  }
        else if (blk < 192) { W = v_w;     Wt = qkvT + 1024*512; K = 512;  N = 512;  tbase = 128; }
        else if (blk < 256) { W = final_w; Wt = finT;            K = 512;  N = 512;  tbase = 192; }
        else if (blk < 384) { W = ffn1_w;  Wt = f1T;             K = 512;  N = 1024; tbase = 256; }
        else if (blk < 512) { W = ffn2_w;  Wt = f2T;             K = 1024; N = 512;  tbase = 384; }
        else                { W = map_w;   Wt = mapT;            K = 256;  N = 512;  tbase = 512; }
        int tloc = blk - tbase;
        int ntn = N >> 6;
        int n0 = (tloc % ntn) * 64, k0 = (tloc / ntn) * 64;
        int j = t & 63, i0 = t >> 6;
        #pragma unroll
        for (int p = 0; p < 16; ++p) {
            int i = i0*16 + p;
            lds[i][j] = W[(size_t)(k0+i)*N + n0 + j];
        }
        __syncthreads();
        int i2 = t & 63, j0 = t >> 6;
        #pragma unroll
        for (int p = 0; p < 16; ++p) {
            int j2 = j0*16 + p;
            Wt[(size_t)(n0+j2)*K + k0 + i2] = f2bf(lds[i2][j2]);
        }
    } else if (blk < 544 + 256) {
        int oc = blk - 544;
        for (int jj = t; jj < 704; jj += 256)
            cwT[(size_t)oc*704 + jj] = (jj < 675) ? f2bf(conv_w[(size_t)oc*675 + jj]) : (u16)0;
    } else {
        for (int jj = t; jj < 1536; jj += 256)
            qkvb[jj] = jj < 512 ? q_b[jj] : (jj < 1024 ? k_b[jj-512] : v_b[jj-1024]);
    }
}

// ---------------------------------------------------------------------------
// im2col: P[(b*25+pos)][j] bf16, K padded to 704
__global__ void im2col_kernel(const float* __restrict__ img, u16* __restrict__ P) {
    int ri = blockIdx.x;               // 0..6399
    int b = ri / 25, pos = ri % 25, ph = pos/5, pw = pos%5;
    for (int j = threadIdx.x; j < 704; j += 256) {
        float v = 0.f;
        if (j < 675) {
            int c = j / 225, rem = j % 225, kh = rem/15, kw = rem%15;
            v = img[(size_t)((b*3+c)*75 + ph*15 + kh)*75 + pw*15 + kw];
        }
        P[(size_t)ri*704 + j] = f2bf(v);
    }
}

// emb rows: cls row + (convout + pe) rows, bf16
__global__ void pe_cls_kernel(const float* __restrict__ co, const float* __restrict__ cls,
                              u16* __restrict__ emb) {
    int t = blockIdx.x;                // 0..6655
    int b = t / SEQ, s = t % SEQ;
    int oc = threadIdx.x;              // 0..255
    float v;
    if (s == 0) v = cls[oc];
    else {
        int pos = s - 1;
        float freq = __powf(10000.0f, -(float)oc / 128.0f);
        float a = (float)pos * freq;
        float pe = 0.7310585786300049f * ((oc & 1) ? __cosf(a) : __sinf(a));
        v = co[(size_t)(b*25+pos)*256 + oc] + pe;
    }
    emb[(size_t)t*256 + oc] = f2bf(v);
}

// ---------------------------------------------------------------------------
// bf16 MFMA GEMM: C[M,N] = op(A[M,K] @ B + bias)*alpha [+res],  B given as Bt[N,K].
// 128x128 tile, BK=64, 512 threads (8 waves, 2x4; 64x32 per wave).
// Staging: global_load_lds width=16, linear LDS dest, PRE-SWIZZLED global source
// (chunk ch' = ch ^ (row&7)); fragment ds_read applies the same XOR -> conflict-free.
template<int RESMODE, int RELU, int OUTBF>
__global__ __launch_bounds__(512) void mfma_gemm(const u16* __restrict__ A, const u16* __restrict__ Bt,
                          const float* __restrict__ bias, const float* __restrict__ res,
                          void* __restrict__ Cout, int M, int N, int K, float alpha) {
    __shared__ __align__(16) u16 As[128*64];
    __shared__ __align__(16) u16 Bs[128*64];
    const int tid = threadIdx.x;
    const int lane = tid & 63;
    const int w = tid >> 6;             // 0..7
    const int wr = (w >> 2) * 64;       // 0 / 64
    const int wc = (w & 3) * 32;        // 0/32/64/96
    const int bm = blockIdx.y * 128, bn = blockIdx.x * 128;

    floatx4 acc[4][2];
    #pragma unroll
    for (int mi = 0; mi < 4; ++mi)
        #pragma unroll
        for (int ni = 0; ni < 2; ++ni)
            acc[mi][ni] = (floatx4){0.f,0.f,0.f,0.f};

    // precompute staging addresses (loop-invariant parts)
    int idx0 = tid, idx1 = 512 + tid;
    int row0 = idx0 >> 3, ch0 = (idx0 & 7) ^ (row0 & 7);
    int row1 = idx1 >> 3, ch1 = (idx1 & 7) ^ (row1 & 7);
    const u16* a0 = &A [(size_t)(bm+row0)*K + ch0*8];
    const u16* a1 = &A [(size_t)(bm+row1)*K + ch1*8];
    const u16* b0 = &Bt[(size_t)(bn+row0)*K + ch0*8];
    const u16* b1 = &Bt[(size_t)(bn+row1)*K + ch1*8];

    for (int k0 = 0; k0 < K; k0 += 64) {
        __syncthreads();   // previous compute done reading LDS
        gload_lds16(a0 + k0, &As[idx0*8]);
        gload_lds16(a1 + k0, &As[idx1*8]);
        gload_lds16(b0 + k0, &Bs[idx0*8]);
        gload_lds16(b1 + k0, &Bs[idx1*8]);
        __syncthreads();   // compiler drains vmcnt(0) here
        #pragma unroll
        for (int kk = 0; kk < 2; ++kk) {
            int ch2 = kk*4 + (lane >> 4);
            short8_t af[4], bf[2];
            #pragma unroll
            for (int mi = 0; mi < 4; ++mi) {
                int row = wr + mi*16 + (lane & 15);
                af[mi] = *(const short8_t*)&As[row*64 + ((ch2 ^ (row & 7))*8)];
            }
            #pragma unroll
            for (int ni = 0; ni < 2; ++ni) {
                int rowb = wc + ni*16 + (lane & 15);
                bf[ni] = *(const short8_t*)&Bs[rowb*64 + ((ch2 ^ (rowb & 7))*8)];
            }
            #pragma unroll
            for (int mi = 0; mi < 4; ++mi)
                #pragma unroll
                for (int ni = 0; ni < 2; ++ni)
                    acc[mi][ni] = __builtin_amdgcn_mfma_f32_16x16x32_bf16(
                        af[mi], bf[ni], acc[mi][ni], 0, 0, 0);
        }
    }

    #pragma unroll
    for (int mi = 0; mi < 4; ++mi) {
        #pragma unroll
        for (int ni = 0; ni < 2; ++ni) {
            int col = bn + wc + ni*16 + (lane & 15);
            float bv = bias ? bias[col] : 0.0f;
            #pragma unroll
            for (int r = 0; r < 4; ++r) {
                int row = bm + wr + mi*16 + (lane >> 4)*4 + r;
                float v = (acc[mi][ni][r] + bv) * alpha;
                if (RELU) v = fmaxf(v, 0.f);
                if (RESMODE == 1)      v += res[(size_t)row*N + col];
                else if (RESMODE == 2) v += res[(size_t)(row/SEQ)*N + col];
                if (OUTBF) ((u16*)Cout)[(size_t)row*N + col] = f2bf(v);
                else       ((float*)Cout)[(size_t)row*N + col] = v;
            }
        }
    }
}

// ---------------------------------------------------------------------------
// per-batch question path
__global__ void que_map_kernel(const float* __restrict__ qst,
                               const float* __restrict__ qrep_w,
                               const float* __restrict__ qrep_b,
                               const float* __restrict__ map_w,
                               const float* __restrict__ map_b,
                               float* __restrict__ quem) {
    int b = blockIdx.x;
    int t = threadIdx.x;
    __shared__ float que[256];
    float acc = qrep_b[t];
    for (int j = 0; j < 18; ++j) acc += qst[b*18 + j] * qrep_w[j*256 + t];
    que[t] = acc;
    __syncthreads();
    for (int n = t; n < DIM; n += 256) {
        float a2 = map_b[n];
        for (int k = 0; k < 256; ++k) a2 += que[k] * map_w[(256 + k)*DIM + n];
        quem[b*DIM + n] = a2;
    }
}

// ---------------------------------------------------------------------------
// LayerNorm over D=512, bf16 out; grid TOK, block 256
__global__ void ln_kernel(const float* __restrict__ x, const float* __restrict__ g,
                          const float* __restrict__ bta, u16* __restrict__ out) {
    int t = blockIdx.x;
    int tid = threadIdx.x;
    const float* xr = x + (size_t)t*DIM;
    float v0 = xr[tid], v1 = xr[tid+256];
    float s = v0 + v1, sq = v0*v0 + v1*v1;
    __shared__ float rs[4], rq[4];
    for (int off = 32; off; off >>= 1) { s += __shfl_down(s, off); sq += __shfl_down(sq, off); }
    int wid = tid >> 6, lane = tid & 63;
    if (lane == 0) { rs[wid] = s; rq[wid] = sq; }
    __syncthreads();
    __shared__ float mean_s, rstd_s;
    if (tid == 0) {
        float ts = rs[0]+rs[1]+rs[2]+rs[3], tq = rq[0]+rq[1]+rq[2]+rq[3];
        float m = ts / DIM;
        float var = tq / DIM - m*m;
        mean_s = m; rstd_s = rsqrtf(var + 1e-5f);
    }
    __syncthreads();
    float m = mean_s, r = rstd_s;
    out[(size_t)t*DIM + tid]       = f2bf((v0 - m)*r*g[tid]     + bta[tid]);
    out[(size_t)t*DIM + tid + 256] = f2bf((v1 - m)*r*g[tid+256] + bta[tid+256]);
}

// ---------------------------------------------------------------------------
// Fully fused attention per batch b (512 threads = 8 waves):
//  (a) wave h computes S_h = softmax_k(Q_h K_h^T / 8) via MFMA -> s_lds [208][28]
//  (b) vw[k,r] = sum_d2 V[k,r*64+d2]*sw[d2]
//  (c) e[hq,r] = sum_k s*vw; comp = softmax_r(e)   (qv & score_b cancel)
//  (d) o[(h,q),d2] = sum_kr (s*comp) @ Vflat  via MFMA (K=208 pad 224)
__global__ __launch_bounds__(512) void attn_fused_kernel(const u16* __restrict__ qkv,
                                                         const float* __restrict__ score_w,
                                                         u16* __restrict__ attn_o) {
    int b = blockIdx.x;
    __shared__ u16 Bt[64*224];        // V as [d2][kr], byte ^= (d2&7)<<4
    __shared__ float s_lds[208*28];   // [(h*26+q)][k], k 26..27 = 0
    __shared__ float vwl[208];        // [k*8+r]
    __shared__ float cmp_lds[208*8];  // [(h,q)][r]
    __shared__ float swl[64];
    int tid = threadIdx.x;
    int lane = tid & 63, w = tid >> 6;

    if (tid < 64) swl[tid] = score_w[32 + tid];
    // V -> Bt (transpose to [d2][kr]); coalesced global bf16 reads
    for (int k = 0; k < 26; ++k) {
        int d2 = tid & 63, r = tid >> 6;
        u16 v = qkv[(size_t)(b*SEQ+k)*1536 + 1024 + tid];
        int bo = (d2*448 + (k*8+r)*2) ^ ((d2 & 7) << 4);
        *(u16*)((char*)Bt + bo) = v;
    }
    {   // zero-pad kr 208..223
        int d2 = tid & 63, kr = 208 + (tid >> 6);
        int bo1 = (d2*448 + kr*2)     ^ ((d2 & 7) << 4);
        int bo2 = (d2*448 + (kr+8)*2) ^ ((d2 & 7) << 4);
        *(u16*)((char*)Bt + bo1) = 0;
        *(u16*)((char*)Bt + bo2) = 0;
    }
    // zero-pad s_lds cols 26,27
    for (int row = tid; row < 208; row += 512) {
        s_lds[row*28 + 26] = 0.f; s_lds[row*28 + 27] = 0.f;
    }

    // ---- (a) QK^T + softmax, wave w handles head h=w ----
    {
        int h = w;
        int col16 = lane & 15, ch = lane >> 4;
        short8_t qf[2][2], kf[2][2];
        #pragma unroll
        for (int mi = 0; mi < 2; ++mi) {
            int q = mi*16 + col16;
            #pragma unroll
            for (int kk = 0; kk < 2; ++kk) {
                if (q < 26)
                    qf[mi][kk] = *(const short8_t*)&qkv[(size_t)(b*SEQ+q)*1536 + h*64 + kk*32 + ch*8];
                else
                    qf[mi][kk] = (short8_t){0,0,0,0,0,0,0,0};
            }
        }
        #pragma unroll
        for (int ni = 0; ni < 2; ++ni) {
            int kq = ni*16 + col16;
            #pragma unroll
            for (int kk = 0; kk < 2; ++kk) {
                if (kq < 26)
                    kf[ni][kk] = *(const short8_t*)&qkv[(size_t)(b*SEQ+kq)*1536 + 512 + h*64 + kk*32 + ch*8];
                else
                    kf[ni][kk] = (short8_t){0,0,0,0,0,0,0,0};
            }
        }
        floatx4 sacc[2][2];
        #pragma unroll
        for (int mi = 0; mi < 2; ++mi)
            #pragma unroll
            for (int ni = 0; ni < 2; ++ni)
                sacc[mi][ni] = (floatx4){0.f,0.f,0.f,0.f};
        #pragma unroll
        for (int kk = 0; kk < 2; ++kk)
            #pragma unroll
            for (int mi = 0; mi < 2; ++mi)
                #pragma unroll
                for (int ni = 0; ni < 2; ++ni)
                    sacc[mi][ni] = __builtin_amdgcn_mfma_f32_16x16x32_bf16(
                        qf[mi][kk], kf[ni][kk], sacc[mi][ni], 0, 0, 0);
        #pragma unroll
        for (int mi = 0; mi < 2; ++mi) {
            #pragma unroll
            for (int r = 0; r < 4; ++r) {
                float s0 = sacc[mi][0][r] * 0.125f;
                float s1 = (col16 < 10) ? sacc[mi][1][r] * 0.125f : -1e30f;
                float mx = fmaxf(s0, s1);
                #pragma unroll
                for (int msk = 1; msk < 16; msk <<= 1) mx = fmaxf(mx, __shfl_xor(mx, msk));
                float e0 = __expf(s0 - mx);
                float e1 = (col16 < 10) ? __expf(s1 - mx) : 0.f;
                float den = e0 + e1;
                #pragma unroll
                for (int msk = 1; msk < 16; msk <<= 1) den += __shfl_xor(den, msk);
                float inv = 1.f / den;
                int q = mi*16 + ch*4 + r;
                if (q < 26) {
                    s_lds[(h*26+q)*28 + col16] = e0 * inv;
                    if (col16 < 10) s_lds[(h*26+q)*28 + 16 + col16] = e1 * inv;
                }
            }
        }
    }
    __syncthreads();

    // ---- (b) vw ----
    if (tid < 208) {
        float acc = 0.f;
        for (int d2 = 0; d2 < 64; ++d2) {
            int bo = (d2*448 + tid*2) ^ ((d2 & 7) << 4);
            acc += bf2f(*(const u16*)((const char*)Bt + bo)) * swl[d2];
        }
        vwl[tid] = acc;
    }
    __syncthreads();

    // ---- (c) e + softmax over r ----
    if (tid < 208) {
        float srow[26];
        #pragma unroll
        for (int k = 0; k < 26; ++k) srow[k] = s_lds[tid*28 + k];
        float e[8];
        #pragma unroll
        for (int r = 0; r < 8; ++r) {
            float a = 0.f;
            #pragma unroll
            for (int k = 0; k < 26; ++k) a += srow[k] * vwl[k*8 + r];
            e[r] = a;
        }
        float m = e[0];
        #pragma unroll
        for (int r = 1; r < 8; ++r) m = fmaxf(m, e[r]);
        float den = 0.f;
        #pragma unroll
        for (int r = 0; r < 8; ++r) { e[r] = __expf(e[r]-m); den += e[r]; }
        float inv = 1.f/den;
        #pragma unroll
        for (int r = 0; r < 8; ++r) cmp_lds[tid*8+r] = e[r]*inv;
    }
    __syncthreads();

    // ---- (d) MFMA: C[208][64] = w2[208][224] @ Vflat[224][64] ----
    int mh = w >> 2, nt = w & 3;
    int ntile0 = nt*16;
    short8_t bfr[7];
    #pragma unroll
    for (int ks = 0; ks < 7; ++ks) {
        int col = ntile0 + (lane & 15);
        int krb = ks*32 + (lane >> 4)*8;
        int bo = (col*448 + krb*2) ^ ((col & 7) << 4);
        bfr[ks] = *(const short8_t*)((const char*)Bt + bo);
    }
    int mt0 = mh ? 7 : 0, mt1 = mh ? 13 : 7;
    for (int mt = mt0; mt < mt1; ++mt) {
        int arow = mt*16 + (lane & 15);
        float c8[8];
        #pragma unroll
        for (int r = 0; r < 8; ++r) c8[r] = cmp_lds[arow*8 + r];
        floatx4 acc = (floatx4){0.f,0.f,0.f,0.f};
        #pragma unroll
        for (int ks = 0; ks < 7; ++ks) {
            int k = ks*4 + (lane >> 4);
            float sv = s_lds[arow*28 + k];
            short8_t af;
            #pragma unroll
            for (int j = 0; j < 8; ++j) af[j] = (short)f2bf(sv * c8[j]);
            acc = __builtin_amdgcn_mfma_f32_16x16x32_bf16(af, bfr[ks], acc, 0, 0, 0);
        }
        int colg = ntile0 + (lane & 15);
        #pragma unroll
        for (int rr = 0; rr < 4; ++rr) {
            int rowg = mt*16 + (lane >> 4)*4 + rr;
            int h = rowg / 26, q = rowg - h*26;
            attn_o[(size_t)(b*SEQ+q)*DIM + h*64 + colg] = f2bf(acc[rr]);
        }
    }
}

// ---------------------------------------------------------------------------
__global__ void head_kernel(const float* __restrict__ x, const float* __restrict__ out_w,
                            const float* __restrict__ out_b, float* __restrict__ y) {
    int b = blockIdx.x;
    int t = threadIdx.x;
    __shared__ float yv[10];
    if (t < 10) {
        float acc = out_b[t];
        const float* xr = x + (size_t)(b*SEQ)*DIM;
        for (int dd = 0; dd < DIM; ++dd) acc += xr[dd]*out_w[dd*10 + t];
        yv[t] = acc;
    }
    __syncthreads();
    if (t < 10) {
        float m = yv[0];
        for (int i = 1; i < 10; ++i) m = fmaxf(m, yv[i]);
        float den = 0.0f;
        for (int i = 0; i < 10; ++i) den += expf(yv[i]-m);
        y[b*10 + t] = yv[t] - m - logf(den);
    }
}

// ---------------------------------------------------------------------------
extern "C" void kernel_launch(void* const* d_in, const int* in_sizes, int n_in,
                              void* d_out, int out_size, void* d_ws, size_t ws_size,
                              hipStream_t stream) {
    const float* img      = (const float*)d_in[0];
    const float* qst      = (const float*)d_in[1];
    const float* conv_w   = (const float*)d_in[2];
    const float* conv_b   = (const float*)d_in[3];
    const float* qrep_w   = (const float*)d_in[4];
    const float* qrep_b   = (const float*)d_in[5];
    const float* cls_tok  = (const float*)d_in[6];
    const float* map_w    = (const float*)d_in[7];
    const float* map_b    = (const float*)d_in[8];
    const float* norm1_g  = (const float*)d_in[9];
    const float* norm1_b  = (const float*)d_in[10];
    const float* norm2_g  = (const float*)d_in[11];
    const float* norm2_b  = (const float*)d_in[12];
    const float* q_w      = (const float*)d_in[13];
    const float* q_b      = (const float*)d_in[14];
    const float* k_w      = (const float*)d_in[15];
    const float* k_b      = (const float*)d_in[16];
    const float* v_w      = (const float*)d_in[17];
    const float* v_b      = (const float*)d_in[18];
    // d_in[19] qv_w, d_in[20] qv_b: cancel in r-softmax — unused
    const float* score_w  = (const float*)d_in[21];
    // d_in[22] score_b: constant along softmax axis — unused
    const float* final_w  = (const float*)d_in[23];
    const float* final_b  = (const float*)d_in[24];
    const float* ffn1_w   = (const float*)d_in[25];
    const float* ffn1_b   = (const float*)d_in[26];
    const float* ffn2_w   = (const float*)d_in[27];
    const float* ffn2_b   = (const float*)d_in[28];
    const float* out_w    = (const float*)d_in[29];
    const float* out_b    = (const float*)d_in[30];

    float* ws = (float*)d_ws;
    size_t o = 0;
    float* x    = ws + o;       o += (size_t)TOK*DIM;
    u16* qkvT   = (u16*)(ws+o); o += (size_t)1536*512/2;
    u16* finT   = (u16*)(ws+o); o += (size_t)512*512/2;
    u16* f1T    = (u16*)(ws+o); o += (size_t)1024*512/2;
    u16* f2T    = (u16*)(ws+o); o += (size_t)512*1024/2;
    u16* mapT   = (u16*)(ws+o); o += (size_t)512*256/2;
    u16* cwT    = (u16*)(ws+o); o += (size_t)256*704/2;
    float* qkvb = ws + o;       o += 1536;
    float* r2   = ws + o;
    // phase-2 layout in r2
    u16*  h_bf    = (u16*)r2;                                  // TOK*512 bf16
    u16*  qkv_bf  = (u16*)(r2 + (size_t)TOK*DIM/2);            // TOK*1536 bf16
    u16*  attn_obf= (u16*)(r2 + (size_t)TOK*DIM/2 + (size_t)TOK*1536/2); // TOK*512 bf16
    u16*  ffbuf   = qkv_bf;                                    // alias (qkv dead in FFN)
    // phase-1 aliases r2
    u16*  Pbuf    = (u16*)r2;                                  // 6400*704 bf16
    float* convout= r2 + (size_t)6400*704/2;
    u16*  emb_bf  = (u16*)(convout + (size_t)6400*256);
    float* quem   = convout + (size_t)6400*256 + (size_t)TOK*256/2;

    // ---- weight prep: one dispatch ----
    prep_all<<<801, 256, 0, stream>>>(q_w, k_w, v_w, final_w, ffn1_w, ffn2_w, map_w, conv_w,
                                      q_b, k_b, v_b, qkvT, finT, f1T, f2T, mapT, cwT, qkvb);

    // ---- phase 1: embedding ----
    im2col_kernel<<<6400, 256, 0, stream>>>(img, Pbuf);
    que_map_kernel<<<NB, 256, 0, stream>>>(qst, qrep_w, qrep_b, map_w, map_b, quem);
    mfma_gemm<0,0,0><<<dim3(2,50), dim3(512), 0, stream>>>(
        Pbuf, cwT, conv_b, nullptr, convout, 6400, 256, 704, 1.0f);
    pe_cls_kernel<<<TOK, 256, 0, stream>>>(convout, cls_tok, emb_bf);
    mfma_gemm<2,0,0><<<dim3(4,52), dim3(512), 0, stream>>>(
        emb_bf, mapT, nullptr, quem, x, TOK, 512, 256, 1.0f);

    // ---- phase 2: 4 transformer iterations ----
    for (int it = 0; it < 4; ++it) {
        ln_kernel<<<TOK, 256, 0, stream>>>(x, norm1_g, norm1_b, h_bf);
        mfma_gemm<0,0,1><<<dim3(12,52), dim3(512), 0, stream>>>(
            h_bf, qkvT, qkvb, nullptr, qkv_bf, TOK, 1536, 512, 1.0f);
        attn_fused_kernel<<<NB, 512, 0, stream>>>(qkv_bf, score_w, attn_obf);
        mfma_gemm<1,0,0><<<dim3(4,52), dim3(512), 0, stream>>>(
            attn_obf, finT, final_b, x, x, TOK, 512, 512, 1.0f);
        ln_kernel<<<TOK, 256, 0, stream>>>(x, norm2_g, norm2_b, h_bf);
        mfma_gemm<0,1,1><<<dim3(8,52), dim3(512), 0, stream>>>(
            h_bf, f1T, ffn1_b, nullptr, ffbuf, TOK, 1024, 512, 1.0f);
        mfma_gemm<1,0,0><<<dim3(4,52), dim3(512), 0, stream>>>(
            ffbuf, f2T, ffn2_b, x, x, TOK, 512, 1024, 1.0f);
    }

    head_kernel<<<NB, 64, 0, stream>>>(x, out_w, out_b, (float*)d_out);
}

// Round 7
// 584.872 us; speedup vs baseline: 8.2691x; 1.0617x over previous
//
#include <hip/hip_runtime.h>
#include <math.h>

#define NB 256
#define SEQ 26
#define TOK (NB*SEQ)   // 6656
#define DIM 512

typedef unsigned short u16;
typedef __attribute__((ext_vector_type(8))) short short8_t;
typedef __attribute__((ext_vector_type(4))) float floatx4;

__device__ inline u16 f2bf(float f) {
    union { float f; unsigned u; } v; v.f = f;
    unsigned r = v.u + 0x7fffu + ((v.u >> 16) & 1u);
    return (u16)(r >> 16);
}
__device__ inline float bf2f(u16 u) {
    union { unsigned u; float f; } v; v.u = ((unsigned)u) << 16; return v.f;
}

__device__ __forceinline__ void gload_lds16(const u16* g, u16* l) {
    __builtin_amdgcn_global_load_lds((const __attribute__((address_space(1))) void*)g,
                                     (__attribute__((address_space(3))) void*)l, 16, 0, 0);
}

// ---------------------------------------------------------------------------
// One-shot weight prep: 64x64 LDS tile transposes (f32 -> bf16 [N][K]),
// conv_w row-copy (pad 675->704), qkv bias concat, cls rows of emb.
// Grid 1057, block 256.
__global__ void prep_all(const float* __restrict__ q_w, const float* __restrict__ k_w,
                         const float* __restrict__ v_w, const float* __restrict__ final_w,
                         const float* __restrict__ ffn1_w, const float* __restrict__ ffn2_w,
                         const float* __restrict__ map_w, const float* __restrict__ conv_w,
                         const float* __restrict__ q_b, const float* __restrict__ k_b,
                         const float* __restrict__ v_b, const float* __restrict__ cls,
                         u16* __restrict__ qkvT, u16* __restrict__ finT,
                         u16* __restrict__ f1T, u16* __restrict__ f2T,
                         u16* __restrict__ mapT, u16* __restrict__ cwT,
                         float* __restrict__ qkvb, u16* __restrict__ emb) {
    __shared__ float lds[64][65];
    int blk = blockIdx.x;
    int t = threadIdx.x;
    if (blk < 544) {
        const float* W; u16* Wt; int K, N, tbase;
        if (blk < 64)       { W = q_w;     Wt = qkvT;            K = 512;  N = 512;  tbase = 0;   }
        else if (blk < 128) { W = k_w;     Wt = qkvT + 512*512;  K = 512;  N = 512;  tbase = 64;  }
        else if (blk < 192) { W = v_w;     Wt = qkvT + 1024*512; K = 512;  N = 512;  tbase = 128; }
        else if (blk < 256) { W = final_w; Wt = finT;            K = 512;  N = 512;  tbase = 192; }
        else if (blk < 384) { W = ffn1_w;  Wt = f1T;             K = 512;  N = 1024; tbase = 256; }
        else if (blk < 512) { W = ffn2_w;  Wt = f2T;             K = 1024; N = 512;  tbase = 384; }
        else                { W = map_w;   Wt = mapT;            K = 256;  N = 512;  tbase = 512; }
        int tloc = blk - tbase;
        int ntn = N >> 6;
        int n0 = (tloc % ntn) * 64, k0 = (tloc / ntn) * 64;
        int j = t & 63, i0 = t >> 6;
        #pragma unroll
        for (int p = 0; p < 16; ++p) {
            int i = i0*16 + p;
            lds[i][j] = W[(size_t)(k0+i)*N + n0 + j];
        }
        __syncthreads();
        int i2 = t & 63, j0 = t >> 6;
        #pragma unroll
        for (int p = 0; p < 16; ++p) {
            int j2 = j0*16 + p;
            Wt[(size_t)(n0+j2)*K + k0 + i2] = f2bf(lds[i2][j2]);
        }
    } else if (blk < 544 + 256) {
        int oc = blk - 544;
        for (int jj = t; jj < 704; jj += 256)
            cwT[(size_t)oc*704 + jj] = (jj < 675) ? f2bf(conv_w[(size_t)oc*675 + jj]) : (u16)0;
    } else if (blk < 544 + 256 + 256) {
        int b = blk - 800;  // cls row for batch b
        emb[(size_t)(b*SEQ)*256 + t] = f2bf(cls[t]);
    } else {
        for (int jj = t; jj < 1536; jj += 256)
            qkvb[jj] = jj < 512 ? q_b[jj] : (jj < 1024 ? k_b[jj-512] : v_b[jj-1024]);
    }
}

// ---------------------------------------------------------------------------
// im2col: P[(b*25+pos)][j] bf16, K padded to 704
__global__ void im2col_kernel(const float* __restrict__ img, u16* __restrict__ P) {
    int ri = blockIdx.x;               // 0..6399
    int b = ri / 25, pos = ri % 25, ph = pos/5, pw = pos%5;
    for (int j = threadIdx.x; j < 704; j += 256) {
        float v = 0.f;
        if (j < 675) {
            int c = j / 225, rem = j % 225, kh = rem/15, kw = rem%15;
            v = img[(size_t)((b*3+c)*75 + ph*15 + kh)*75 + pw*15 + kw];
        }
        P[(size_t)ri*704 + j] = f2bf(v);
    }
}

// ---------------------------------------------------------------------------
// bf16 MFMA GEMM: C[M,N] = op(A[M,K] @ B + bias)*alpha [+res],  B given as Bt[N,K].
// 128x128 tile, BK=64, 512 threads (8 waves, 2x4; 64x32 per wave).
// Double-buffered LDS: prefetch next K-tile via global_load_lds BEFORE computing
// current tile; one __syncthreads (vmcnt+lgkm drain) per K-step.
// Staging: linear LDS dest, PRE-SWIZZLED global source (ch' = ch ^ (row&7));
// fragment ds_read applies the same XOR -> conflict-free (both-sides rule).
// RESMODE: 0 none, 1 +res[row*N+col], 2 +res[(row/26)*N+col],
//          3 conv->emb: out row b*26+1+pos (+pe), bf16.
template<int RESMODE, int RELU, int OUTBF>
__global__ __launch_bounds__(512) void mfma_gemm(const u16* __restrict__ A, const u16* __restrict__ Bt,
                          const float* __restrict__ bias, const float* __restrict__ res,
                          void* __restrict__ Cout, int M, int N, int K, float alpha) {
    __shared__ __align__(16) u16 As[2][128*64];
    __shared__ __align__(16) u16 Bs[2][128*64];
    const int tid = threadIdx.x;
    const int lane = tid & 63;
    const int w = tid >> 6;             // 0..7
    const int wr = (w >> 2) * 64;       // 0 / 64
    const int wc = (w & 3) * 32;        // 0/32/64/96
    const int bm = blockIdx.y * 128, bn = blockIdx.x * 128;

    floatx4 acc[4][2];
    #pragma unroll
    for (int mi = 0; mi < 4; ++mi)
        #pragma unroll
        for (int ni = 0; ni < 2; ++ni)
            acc[mi][ni] = (floatx4){0.f,0.f,0.f,0.f};

    // staging addresses (loop-invariant)
    int idx0 = tid, idx1 = 512 + tid;
    int row0 = idx0 >> 3, ch0 = (idx0 & 7) ^ (row0 & 7);
    int row1 = idx1 >> 3, ch1 = (idx1 & 7) ^ (row1 & 7);
    const u16* a0 = &A [(size_t)(bm+row0)*K + ch0*8];
    const u16* a1 = &A [(size_t)(bm+row1)*K + ch1*8];
    const u16* b0 = &Bt[(size_t)(bn+row0)*K + ch0*8];
    const u16* b1 = &Bt[(size_t)(bn+row1)*K + ch1*8];

    const int nt = K >> 6;
    // prologue: stage tile 0 into buf 0
    gload_lds16(a0, &As[0][idx0*8]);
    gload_lds16(a1, &As[0][idx1*8]);
    gload_lds16(b0, &Bs[0][idx0*8]);
    gload_lds16(b1, &Bs[0][idx1*8]);
    __syncthreads();

    for (int t = 0; t < nt; ++t) {
        const int cur = t & 1;
        if (t + 1 < nt) {   // prefetch next tile into other buffer (overlaps MFMA)
            int off = (t + 1) << 6;
            gload_lds16(a0 + off, &As[cur^1][idx0*8]);
            gload_lds16(a1 + off, &As[cur^1][idx1*8]);
            gload_lds16(b0 + off, &Bs[cur^1][idx0*8]);
            gload_lds16(b1 + off, &Bs[cur^1][idx1*8]);
        }
        #pragma unroll
        for (int kk = 0; kk < 2; ++kk) {
            int ch2 = kk*4 + (lane >> 4);
            short8_t af[4], bf[2];
            #pragma unroll
            for (int mi = 0; mi < 4; ++mi) {
                int row = wr + mi*16 + (lane & 15);
                af[mi] = *(const short8_t*)&As[cur][row*64 + ((ch2 ^ (row & 7))*8)];
            }
            #pragma unroll
            for (int ni = 0; ni < 2; ++ni) {
                int rowb = wc + ni*16 + (lane & 15);
                bf[ni] = *(const short8_t*)&Bs[cur][rowb*64 + ((ch2 ^ (rowb & 7))*8)];
            }
            #pragma unroll
            for (int mi = 0; mi < 4; ++mi)
                #pragma unroll
                for (int ni = 0; ni < 2; ++ni)
                    acc[mi][ni] = __builtin_amdgcn_mfma_f32_16x16x32_bf16(
                        af[mi], bf[ni], acc[mi][ni], 0, 0, 0);
        }
        __syncthreads();   // drains prefetch vmcnt + all lgkm; next tile ready
    }

    #pragma unroll
    for (int mi = 0; mi < 4; ++mi) {
        #pragma unroll
        for (int ni = 0; ni < 2; ++ni) {
            int col = bn + wc + ni*16 + (lane & 15);
            float bv = bias ? bias[col] : 0.0f;
            #pragma unroll
            for (int r = 0; r < 4; ++r) {
                int row = bm + wr + mi*16 + (lane >> 4)*4 + r;
                float v = (acc[mi][ni][r] + bv) * alpha;
                if (RELU) v = fmaxf(v, 0.f);
                if (RESMODE == 1)      v += res[(size_t)row*N + col];
                else if (RESMODE == 2) v += res[(size_t)(row/SEQ)*N + col];
                if (RESMODE == 3) {
                    // conv output row = b*25+pos -> emb row b*26+1+pos, plus pe
                    int bb = row / 25, pos = row - bb*25;
                    float freq = __powf(10000.0f, -(float)col / 128.0f);
                    float a = (float)pos * freq;
                    float pe = 0.7310585786300049f * ((col & 1) ? __cosf(a) : __sinf(a));
                    ((u16*)Cout)[(size_t)(bb*SEQ + 1 + pos)*256 + col] = f2bf(v + pe);
                } else if (OUTBF) {
                    ((u16*)Cout)[(size_t)row*N + col] = f2bf(v);
                } else {
                    ((float*)Cout)[(size_t)row*N + col] = v;
                }
            }
        }
    }
}

// ---------------------------------------------------------------------------
// per-batch question path
__global__ void que_map_kernel(const float* __restrict__ qst,
                               const float* __restrict__ qrep_w,
                               const float* __restrict__ qrep_b,
                               const float* __restrict__ map_w,
                               const float* __restrict__ map_b,
                               float* __restrict__ quem) {
    int b = blockIdx.x;
    int t = threadIdx.x;
    __shared__ float que[256];
    float acc = qrep_b[t];
    for (int j = 0; j < 18; ++j) acc += qst[b*18 + j] * qrep_w[j*256 + t];
    que[t] = acc;
    __syncthreads();
    for (int n = t; n < DIM; n += 256) {
        float a2 = map_b[n];
        for (int k = 0; k < 256; ++k) a2 += que[k] * map_w[(256 + k)*DIM + n];
        quem[b*DIM + n] = a2;
    }
}

// ---------------------------------------------------------------------------
// LayerNorm over D=512, bf16 out; grid TOK, block 256
__global__ void ln_kernel(const float* __restrict__ x, const float* __restrict__ g,
                          const float* __restrict__ bta, u16* __restrict__ out) {
    int t = blockIdx.x;
    int tid = threadIdx.x;
    const float* xr = x + (size_t)t*DIM;
    float v0 = xr[tid], v1 = xr[tid+256];
    float s = v0 + v1, sq = v0*v0 + v1*v1;
    __shared__ float rs[4], rq[4];
    for (int off = 32; off; off >>= 1) { s += __shfl_down(s, off); sq += __shfl_down(sq, off); }
    int wid = tid >> 6, lane = tid & 63;
    if (lane == 0) { rs[wid] = s; rq[wid] = sq; }
    __syncthreads();
    __shared__ float mean_s, rstd_s;
    if (tid == 0) {
        float ts = rs[0]+rs[1]+rs[2]+rs[3], tq = rq[0]+rq[1]+rq[2]+rq[3];
        float m = ts / DIM;
        float var = tq / DIM - m*m;
        mean_s = m; rstd_s = rsqrtf(var + 1e-5f);
    }
    __syncthreads();
    float m = mean_s, r = rstd_s;
    out[(size_t)t*DIM + tid]       = f2bf((v0 - m)*r*g[tid]     + bta[tid]);
    out[(size_t)t*DIM + tid + 256] = f2bf((v1 - m)*r*g[tid+256] + bta[tid+256]);
}

// ---------------------------------------------------------------------------
// Fully fused attention per batch b (512 threads = 8 waves):
//  (a) wave h computes S_h = softmax_k(Q_h K_h^T / 8) via MFMA -> s_lds [208][28]
//  (b) vw[k,r] = sum_d2 V[k,r*64+d2]*sw[d2]
//  (c) e[hq,r] = sum_k s*vw; comp = softmax_r(e)   (qv & score_b cancel)
//  (d) o[(h,q),d2] = sum_kr (s*comp) @ Vflat  via MFMA (K=208 pad 224)
__global__ __launch_bounds__(512) void attn_fused_kernel(const u16* __restrict__ qkv,
                                                         const float* __restrict__ score_w,
                                                         u16* __restrict__ attn_o) {
    int b = blockIdx.x;
    __shared__ u16 Bt[64*224];        // V as [d2][kr], byte ^= (d2&7)<<4
    __shared__ float s_lds[208*28];   // [(h*26+q)][k], k 26..27 = 0
    __shared__ float vwl[208];        // [k*8+r]
    __shared__ float cmp_lds[208*8];  // [(h,q)][r]
    __shared__ float swl[64];
    int tid = threadIdx.x;
    int lane = tid & 63, w = tid >> 6;

    if (tid < 64) swl[tid] = score_w[32 + tid];
    // V -> Bt (transpose to [d2][kr]); coalesced global bf16 reads
    for (int k = 0; k < 26; ++k) {
        int d2 = tid & 63, r = tid >> 6;
        u16 v = qkv[(size_t)(b*SEQ+k)*1536 + 1024 + tid];
        int bo = (d2*448 + (k*8+r)*2) ^ ((d2 & 7) << 4);
        *(u16*)((char*)Bt + bo) = v;
    }
    {   // zero-pad kr 208..223
        int d2 = tid & 63, kr = 208 + (tid >> 6);
        int bo1 = (d2*448 + kr*2)     ^ ((d2 & 7) << 4);
        int bo2 = (d2*448 + (kr+8)*2) ^ ((d2 & 7) << 4);
        *(u16*)((char*)Bt + bo1) = 0;
        *(u16*)((char*)Bt + bo2) = 0;
    }
    // zero-pad s_lds cols 26,27
    for (int row = tid; row < 208; row += 512) {
        s_lds[row*28 + 26] = 0.f; s_lds[row*28 + 27] = 0.f;
    }

    // ---- (a) QK^T + softmax, wave w handles head h=w ----
    {
        int h = w;
        int col16 = lane & 15, ch = lane >> 4;
        short8_t qf[2][2], kf[2][2];
        #pragma unroll
        for (int mi = 0; mi < 2; ++mi) {
            int q = mi*16 + col16;
            #pragma unroll
            for (int kk = 0; kk < 2; ++kk) {
                if (q < 26)
                    qf[mi][kk] = *(const short8_t*)&qkv[(size_t)(b*SEQ+q)*1536 + h*64 + kk*32 + ch*8];
                else
                    qf[mi][kk] = (short8_t){0,0,0,0,0,0,0,0};
            }
        }
        #pragma unroll
        for (int ni = 0; ni < 2; ++ni) {
            int kq = ni*16 + col16;
            #pragma unroll
            for (int kk = 0; kk < 2; ++kk) {
                if (kq < 26)
                    kf[ni][kk] = *(const short8_t*)&qkv[(size_t)(b*SEQ+kq)*1536 + 512 + h*64 + kk*32 + ch*8];
                else
                    kf[ni][kk] = (short8_t){0,0,0,0,0,0,0,0};
            }
        }
        floatx4 sacc[2][2];
        #pragma unroll
        for (int mi = 0; mi < 2; ++mi)
            #pragma unroll
            for (int ni = 0; ni < 2; ++ni)
                sacc[mi][ni] = (floatx4){0.f,0.f,0.f,0.f};
        #pragma unroll
        for (int kk = 0; kk < 2; ++kk)
            #pragma unroll
            for (int mi = 0; mi < 2; ++mi)
                #pragma unroll
                for (int ni = 0; ni < 2; ++ni)
                    sacc[mi][ni] = __builtin_amdgcn_mfma_f32_16x16x32_bf16(
                        qf[mi][kk], kf[ni][kk], sacc[mi][ni], 0, 0, 0);
        #pragma unroll
        for (int mi = 0; mi < 2; ++mi) {
            #pragma unroll
            for (int r = 0; r < 4; ++r) {
                float s0 = sacc[mi][0][r] * 0.125f;
                float s1 = (col16 < 10) ? sacc[mi][1][r] * 0.125f : -1e30f;
                float mx = fmaxf(s0, s1);
                #pragma unroll
                for (int msk = 1; msk < 16; msk <<= 1) mx = fmaxf(mx, __shfl_xor(mx, msk));
                float e0 = __expf(s0 - mx);
                float e1 = (col16 < 10) ? __expf(s1 - mx) : 0.f;
                float den = e0 + e1;
                #pragma unroll
                for (int msk = 1; msk < 16; msk <<= 1) den += __shfl_xor(den, msk);
                float inv = 1.f / den;
                int q = mi*16 + ch*4 + r;
                if (q < 26) {
                    s_lds[(h*26+q)*28 + col16] = e0 * inv;
                    if (col16 < 10) s_lds[(h*26+q)*28 + 16 + col16] = e1 * inv;
                }
            }
        }
    }
    __syncthreads();

    // ---- (b) vw ----
    if (tid < 208) {
        float acc = 0.f;
        for (int d2 = 0; d2 < 64; ++d2) {
            int bo = (d2*448 + tid*2) ^ ((d2 & 7) << 4);
            acc += bf2f(*(const u16*)((const char*)Bt + bo)) * swl[d2];
        }
        vwl[tid] = acc;
    }
    __syncthreads();

    // ---- (c) e + softmax over r ----
    if (tid < 208) {
        float srow[26];
        #pragma unroll
        for (int k = 0; k < 26; ++k) srow[k] = s_lds[tid*28 + k];
        float e[8];
        #pragma unroll
        for (int r = 0; r < 8; ++r) {
            float a = 0.f;
            #pragma unroll
            for (int k = 0; k < 26; ++k) a += srow[k] * vwl[k*8 + r];
            e[r] = a;
        }
        float m = e[0];
        #pragma unroll
        for (int r = 1; r < 8; ++r) m = fmaxf(m, e[r]);
        float den = 0.f;
        #pragma unroll
        for (int r = 0; r < 8; ++r) { e[r] = __expf(e[r]-m); den += e[r]; }
        float inv = 1.f/den;
        #pragma unroll
        for (int r = 0; r < 8; ++r) cmp_lds[tid*8+r] = e[r]*inv;
    }
    __syncthreads();

    // ---- (d) MFMA: C[208][64] = w2[208][224] @ Vflat[224][64] ----
    int mh = w >> 2, nt = w & 3;
    int ntile0 = nt*16;
    short8_t bfr[7];
    #pragma unroll
    for (int ks = 0; ks < 7; ++ks) {
        int col = ntile0 + (lane & 15);
        int krb = ks*32 + (lane >> 4)*8;
        int bo = (col*448 + krb*2) ^ ((col & 7) << 4);
        bfr[ks] = *(const short8_t*)((const char*)Bt + bo);
    }
    int mt0 = mh ? 7 : 0, mt1 = mh ? 13 : 7;
    for (int mt = mt0; mt < mt1; ++mt) {
        int arow = mt*16 + (lane & 15);
        float c8[8];
        #pragma unroll
        for (int r = 0; r < 8; ++r) c8[r] = cmp_lds[arow*8 + r];
        floatx4 acc = (floatx4){0.f,0.f,0.f,0.f};
        #pragma unroll
        for (int ks = 0; ks < 7; ++ks) {
            int k = ks*4 + (lane >> 4);
            float sv = s_lds[arow*28 + k];
            short8_t af;
            #pragma unroll
            for (int j = 0; j < 8; ++j) af[j] = (short)f2bf(sv * c8[j]);
            acc = __builtin_amdgcn_mfma_f32_16x16x32_bf16(af, bfr[ks], acc, 0, 0, 0);
        }
        int colg = ntile0 + (lane & 15);
        #pragma unroll
        for (int rr = 0; rr < 4; ++rr) {
            int rowg = mt*16 + (lane >> 4)*4 + rr;
            int h = rowg / 26, q = rowg - h*26;
            attn_o[(size_t)(b*SEQ+q)*DIM + h*64 + colg] = f2bf(acc[rr]);
        }
    }
}

// ---------------------------------------------------------------------------
__global__ void head_kernel(const float* __restrict__ x, const float* __restrict__ out_w,
                            const float* __restrict__ out_b, float* __restrict__ y) {
    int b = blockIdx.x;
    int t = threadIdx.x;
    __shared__ float yv[10];
    if (t < 10) {
        float acc = out_b[t];
        const float* xr = x + (size_t)(b*SEQ)*DIM;
        for (int dd = 0; dd < DIM; ++dd) acc += xr[dd]*out_w[dd*10 + t];
        yv[t] = acc;
    }
    __syncthreads();
    if (t < 10) {
        float m = yv[0];
        for (int i = 1; i < 10; ++i) m = fmaxf(m, yv[i]);
        float den = 0.0f;
        for (int i = 0; i < 10; ++i) den += expf(yv[i]-m);
        y[b*10 + t] = yv[t] - m - logf(den);
    }
}

// ---------------------------------------------------------------------------
extern "C" void kernel_launch(void* const* d_in, const int* in_sizes, int n_in,
                              void* d_out, int out_size, void* d_ws, size_t ws_size,
                              hipStream_t stream) {
    const float* img      = (const float*)d_in[0];
    const float* qst      = (const float*)d_in[1];
    const float* conv_w   = (const float*)d_in[2];
    const float* conv_b   = (const float*)d_in[3];
    const float* qrep_w   = (const float*)d_in[4];
    const float* qrep_b   = (const float*)d_in[5];
    const float* cls_tok  = (const float*)d_in[6];
    const float* map_w    = (const float*)d_in[7];
    const float* map_b    = (const float*)d_in[8];
    const float* norm1_g  = (const float*)d_in[9];
    const float* norm1_b  = (const float*)d_in[10];
    const float* norm2_g  = (const float*)d_in[11];
    const float* norm2_b  = (const float*)d_in[12];
    const float* q_w      = (const float*)d_in[13];
    const float* q_b      = (const float*)d_in[14];
    const float* k_w      = (const float*)d_in[15];
    const float* k_b      = (const float*)d_in[16];
    const float* v_w      = (const float*)d_in[17];
    const float* v_b      = (const float*)d_in[18];
    // d_in[19] qv_w, d_in[20] qv_b: cancel in r-softmax — unused
    const float* score_w  = (const float*)d_in[21];
    // d_in[22] score_b: constant along softmax axis — unused
    const float* final_w  = (const float*)d_in[23];
    const float* final_b  = (const float*)d_in[24];
    const float* ffn1_w   = (const float*)d_in[25];
    const float* ffn1_b   = (const float*)d_in[26];
    const float* ffn2_w   = (const float*)d_in[27];
    const float* ffn2_b   = (const float*)d_in[28];
    const float* out_w    = (const float*)d_in[29];
    const float* out_b    = (const float*)d_in[30];

    float* ws = (float*)d_ws;
    size_t o = 0;
    float* x    = ws + o;       o += (size_t)TOK*DIM;
    u16* qkvT   = (u16*)(ws+o); o += (size_t)1536*512/2;
    u16* finT   = (u16*)(ws+o); o += (size_t)512*512/2;
    u16* f1T    = (u16*)(ws+o); o += (size_t)1024*512/2;
    u16* f2T    = (u16*)(ws+o); o += (size_t)512*1024/2;
    u16* mapT   = (u16*)(ws+o); o += (size_t)512*256/2;
    u16* cwT    = (u16*)(ws+o); o += (size_t)256*704/2;
    float* qkvb = ws + o;       o += 1536;
    float* r2   = ws + o;
    // phase-2 layout in r2
    u16*  h_bf    = (u16*)r2;                                  // TOK*512 bf16
    u16*  qkv_bf  = (u16*)(r2 + (size_t)TOK*DIM/2);            // TOK*1536 bf16
    u16*  attn_obf= (u16*)(r2 + (size_t)TOK*DIM/2 + (size_t)TOK*1536/2); // TOK*512 bf16
    u16*  ffbuf   = qkv_bf;                                    // alias (qkv dead in FFN)
    // phase-1 aliases r2
    u16*  Pbuf    = (u16*)r2;                                  // 6400*704 bf16
    u16*  emb_bf  = (u16*)(r2 + (size_t)6400*704/2);           // TOK*256 bf16
    float* quem   = r2 + (size_t)6400*704/2 + (size_t)TOK*256/2;

    // ---- weight prep + cls rows: one dispatch ----
    prep_all<<<1057, 256, 0, stream>>>(q_w, k_w, v_w, final_w, ffn1_w, ffn2_w, map_w, conv_w,
                                       q_b, k_b, v_b, cls_tok,
                                       qkvT, finT, f1T, f2T, mapT, cwT, qkvb, emb_bf);

    // ---- phase 1: embedding ----
    im2col_kernel<<<6400, 256, 0, stream>>>(img, Pbuf);
    que_map_kernel<<<NB, 256, 0, stream>>>(qst, qrep_w, qrep_b, map_w, map_b, quem);
    // conv patch-GEMM writes emb rows directly (+pe), bf16
    mfma_gemm<3,0,1><<<dim3(2,50), dim3(512), 0, stream>>>(
        Pbuf, cwT, conv_b, nullptr, emb_bf, 6400, 256, 704, 1.0f);
    mfma_gemm<2,0,0><<<dim3(4,52), dim3(512), 0, stream>>>(
        emb_bf, mapT, nullptr, quem, x, TOK, 512, 256, 1.0f);

    // ---- phase 2: 4 transformer iterations ----
    for (int it = 0; it < 4; ++it) {
        ln_kernel<<<TOK, 256, 0, stream>>>(x, norm1_g, norm1_b, h_bf);
        mfma_gemm<0,0,1><<<dim3(12,52), dim3(512), 0, stream>>>(
            h_bf, qkvT, qkvb, nullptr, qkv_bf, TOK, 1536, 512, 1.0f);
        attn_fused_kernel<<<NB, 512, 0, stream>>>(qkv_bf, score_w, attn_obf);
        mfma_gemm<1,0,0><<<dim3(4,52), dim3(512), 0, stream>>>(
            attn_obf, finT, final_b, x, x, TOK, 512, 512, 1.0f);
        ln_kernel<<<TOK, 256, 0, stream>>>(x, norm2_g, norm2_b, h_bf);
        mfma_gemm<0,1,1><<<dim3(8,52), dim3(512), 0, stream>>>(
            h_bf, f1T, ffn1_b, nullptr, ffbuf, TOK, 1024, 512, 1.0f);
        mfma_gemm<1,0,0><<<dim3(4,52), dim3(512), 0, stream>>>(
            ffbuf, f2T, ffn2_b, x, x, TOK, 512, 1024, 1.0f);
    }

    head_kernel<<<NB, 64, 0, stream>>>(x, out_w, out_b, (float*)d_out);
}

// Round 9
// 540.901 us; speedup vs baseline: 8.9413x; 1.0813x over previous
//
#include <hip/hip_runtime.h>
#include <math.h>

#define NB 256
#define SEQ 26
#define TOK (NB*SEQ)   // 6656
#define DIM 512

typedef unsigned short u16;
typedef __attribute__((ext_vector_type(8))) short short8_t;
typedef __attribute__((ext_vector_type(4))) float floatx4;

__device__ inline u16 f2bf(float f) {
    union { float f; unsigned u; } v; v.f = f;
    unsigned r = v.u + 0x7fffu + ((v.u >> 16) & 1u);
    return (u16)(r >> 16);
}
__device__ inline float bf2f(u16 u) {
    union { unsigned u; float f; } v; v.u = ((unsigned)u) << 16; return v.f;
}

__device__ __forceinline__ void gload_lds16(const u16* g, u16* l) {
    __builtin_amdgcn_global_load_lds((const __attribute__((address_space(1))) void*)g,
                                     (__attribute__((address_space(3))) void*)l, 16, 0, 0);
}

// ---------------------------------------------------------------------------
// One-shot prep: weight transposes (f32->bf16 [N][K]), conv_w pad-copy,
// cls rows, qkv bias concat, AND the per-batch question path (que_map).
// Grid 1313, block 256.
__global__ void prep_all(const float* __restrict__ q_w, const float* __restrict__ k_w,
                         const float* __restrict__ v_w, const float* __restrict__ final_w,
                         const float* __restrict__ ffn1_w, const float* __restrict__ ffn2_w,
                         const float* __restrict__ map_w, const float* __restrict__ conv_w,
                         const float* __restrict__ q_b, const float* __restrict__ k_b,
                         const float* __restrict__ v_b, const float* __restrict__ cls,
                         const float* __restrict__ qst, const float* __restrict__ qrep_w,
                         const float* __restrict__ qrep_b, const float* __restrict__ map_b,
                         u16* __restrict__ qkvT, u16* __restrict__ finT,
                         u16* __restrict__ f1T, u16* __restrict__ f2T,
                         u16* __restrict__ mapT, u16* __restrict__ cwT,
                         float* __restrict__ qkvb, u16* __restrict__ emb,
                         float* __restrict__ quem) {
    __shared__ float lds[64][65];
    __shared__ float que[256];
    int blk = blockIdx.x;
    int t = threadIdx.x;
    if (blk < 544) {
        const float* W; u16* Wt; int K, N, tbase;
        if (blk < 64)       { W = q_w;     Wt = qkvT;            K = 512;  N = 512;  tbase = 0;   }
        else if (blk < 128) { W = k_w;     Wt = qkvT + 512*512;  K = 512;  N = 512;  tbase = 64;  }
        else if (blk < 192) { W = v_w;     Wt = qkvT + 1024*512; K = 512;  N = 512;  tbase = 128; }
        else if (blk < 256) { W = final_w; Wt = finT;            K = 512;  N = 512;  tbase = 192; }
        else if (blk < 384) { W = ffn1_w;  Wt = f1T;             K = 512;  N = 1024; tbase = 256; }
        else if (blk < 512) { W = ffn2_w;  Wt = f2T;             K = 1024; N = 512;  tbase = 384; }
        else                { W = map_w;   Wt = mapT;            K = 256;  N = 512;  tbase = 512; }
        int tloc = blk - tbase;
        int ntn = N >> 6;
        int n0 = (tloc % ntn) * 64, k0 = (tloc / ntn) * 64;
        int j = t & 63, i0 = t >> 6;
        #pragma unroll
        for (int p = 0; p < 16; ++p) {
            int i = i0*16 + p;
            lds[i][j] = W[(size_t)(k0+i)*N + n0 + j];
        }
        __syncthreads();
        int i2 = t & 63, j0 = t >> 6;
        #pragma unroll
        for (int p = 0; p < 16; ++p) {
            int j2 = j0*16 + p;
            Wt[(size_t)(n0+j2)*K + k0 + i2] = f2bf(lds[i2][j2]);
        }
    } else if (blk < 800) {
        int oc = blk - 544;
        for (int jj = t; jj < 704; jj += 256)
            cwT[(size_t)oc*704 + jj] = (jj < 675) ? f2bf(conv_w[(size_t)oc*675 + jj]) : (u16)0;
    } else if (blk < 1056) {
        int b = blk - 800;  // cls row for batch b
        emb[(size_t)(b*SEQ)*256 + t] = f2bf(cls[t]);
    } else if (blk == 1056) {
        for (int jj = t; jj < 1536; jj += 256)
            qkvb[jj] = jj < 512 ? q_b[jj] : (jj < 1024 ? k_b[jj-512] : v_b[jj-1024]);
    } else {
        int b = blk - 1057;  // question path for batch b
        float acc = qrep_b[t];
        for (int j = 0; j < 18; ++j) acc += qst[b*18 + j] * qrep_w[j*256 + t];
        que[t] = acc;
        __syncthreads();
        for (int n = t; n < DIM; n += 256) {
            float a2 = map_b[n];
            for (int k = 0; k < 256; ++k) a2 += que[k] * map_w[(256 + k)*DIM + n];
            quem[b*DIM + n] = a2;
        }
    }
}

// ---------------------------------------------------------------------------
// im2col: P[(b*25+pos)][j] bf16, K padded to 704
__global__ void im2col_kernel(const float* __restrict__ img, u16* __restrict__ P) {
    int ri = blockIdx.x;               // 0..6399
    int b = ri / 25, pos = ri % 25, ph = pos/5, pw = pos%5;
    for (int j = threadIdx.x; j < 704; j += 256) {
        float v = 0.f;
        if (j < 675) {
            int c = j / 225, rem = j % 225, kh = rem/15, kw = rem%15;
            v = img[(size_t)((b*3+c)*75 + ph*15 + kh)*75 + pw*15 + kw];
        }
        P[(size_t)ri*704 + j] = f2bf(v);
    }
}

// ---------------------------------------------------------------------------
// bf16 MFMA GEMM: C[M,N] = op(A[M,K] @ B + bias)*alpha [+res],  B given as Bt[N,K].
// BM x 128 tile (BM=128 or 64), BK=64, 512 threads (8 waves, 2x4).
// Double-buffered LDS; global_load_lds width=16; linear LDS dest with
// PRE-SWIZZLED global source (ch' = ch ^ (row&7)); ds_read applies same XOR.
// RESMODE: 0 none, 1 +res[row*N+col], 2 +res[(row/26)*N+col],
//          3 conv->emb: out row b*26+1+pos (+pe), bf16.
template<int BM, int RESMODE, int RELU, int OUTBF>
__global__ __launch_bounds__(512) void mfma_gemm(const u16* __restrict__ A, const u16* __restrict__ Bt,
                          const float* __restrict__ bias, const float* __restrict__ res,
                          void* __restrict__ Cout, int M, int N, int K, float alpha) {
    constexpr int MI  = BM / 32;   // acc row-tiles per wave
    constexpr int ALD = BM / 64;   // A gloads per thread
    __shared__ __align__(16) u16 As[2][BM*64];
    __shared__ __align__(16) u16 Bs[2][128*64];
    const int tid = threadIdx.x;
    const int lane = tid & 63;
    const int w = tid >> 6;             // 0..7
    const int wr = (w >> 2) * (MI*16);
    const int wc = (w & 3) * 32;
    const int bm = blockIdx.y * BM, bn = blockIdx.x * 128;

    floatx4 acc[MI][2];
    #pragma unroll
    for (int mi = 0; mi < MI; ++mi)
        #pragma unroll
        for (int ni = 0; ni < 2; ++ni)
            acc[mi][ni] = (floatx4){0.f,0.f,0.f,0.f};

    // staging addresses (loop-invariant)
    const u16* aptr[ALD];
    int aidx[ALD];
    #pragma unroll
    for (int s = 0; s < ALD; ++s) {
        int idx = s*512 + tid;
        int row = idx >> 3, ch = (idx & 7) ^ (row & 7);
        aptr[s] = &A[(size_t)(bm+row)*K + ch*8];
        aidx[s] = idx;
    }
    const u16* bptr[2];
    int bidx[2];
    #pragma unroll
    for (int s = 0; s < 2; ++s) {
        int idx = s*512 + tid;
        int row = idx >> 3, ch = (idx & 7) ^ (row & 7);
        bptr[s] = &Bt[(size_t)(bn+row)*K + ch*8];
        bidx[s] = idx;
    }

    const int nt = K >> 6;
    // prologue: stage tile 0 into buf 0
    #pragma unroll
    for (int s = 0; s < ALD; ++s) gload_lds16(aptr[s], &As[0][aidx[s]*8]);
    #pragma unroll
    for (int s = 0; s < 2; ++s)   gload_lds16(bptr[s], &Bs[0][bidx[s]*8]);
    __syncthreads();

    for (int t = 0; t < nt; ++t) {
        const int cur = t & 1;
        if (t + 1 < nt) {   // prefetch next tile into other buffer (overlaps MFMA)
            int off = (t + 1) << 6;
            #pragma unroll
            for (int s = 0; s < ALD; ++s) gload_lds16(aptr[s] + off, &As[cur^1][aidx[s]*8]);
            #pragma unroll
            for (int s = 0; s < 2; ++s)   gload_lds16(bptr[s] + off, &Bs[cur^1][bidx[s]*8]);
        }
        #pragma unroll
        for (int kk = 0; kk < 2; ++kk) {
            int ch2 = kk*4 + (lane >> 4);
            short8_t af[MI], bf[2];
            #pragma unroll
            for (int mi = 0; mi < MI; ++mi) {
                int row = wr + mi*16 + (lane & 15);
                af[mi] = *(const short8_t*)&As[cur][row*64 + ((ch2 ^ (row & 7))*8)];
            }
            #pragma unroll
            for (int ni = 0; ni < 2; ++ni) {
                int rowb = wc + ni*16 + (lane & 15);
                bf[ni] = *(const short8_t*)&Bs[cur][rowb*64 + ((ch2 ^ (rowb & 7))*8)];
            }
            #pragma unroll
            for (int mi = 0; mi < MI; ++mi)
                #pragma unroll
                for (int ni = 0; ni < 2; ++ni)
                    acc[mi][ni] = __builtin_amdgcn_mfma_f32_16x16x32_bf16(
                        af[mi], bf[ni], acc[mi][ni], 0, 0, 0);
        }
        __syncthreads();   // drains prefetch vmcnt + all lgkm; next tile ready
    }

    #pragma unroll
    for (int mi = 0; mi < MI; ++mi) {
        #pragma unroll
        for (int ni = 0; ni < 2; ++ni) {
            int col = bn + wc + ni*16 + (lane & 15);
            float bv = bias ? bias[col] : 0.0f;
            #pragma unroll
            for (int r = 0; r < 4; ++r) {
                int row = bm + wr + mi*16 + (lane >> 4)*4 + r;
                float v = (acc[mi][ni][r] + bv) * alpha;
                if (RELU) v = fmaxf(v, 0.f);
                if (RESMODE == 1)      v += res[(size_t)row*N + col];
                else if (RESMODE == 2) v += res[(size_t)(row/SEQ)*N + col];
                if (RESMODE == 3) {
                    // conv output row = b*25+pos -> emb row b*26+1+pos, plus pe
                    int bb = row / 25, pos = row - bb*25;
                    float freq = __powf(10000.0f, -(float)col / 128.0f);
                    float a = (float)pos * freq;
                    float pe = 0.7310585786300049f * ((col & 1) ? __cosf(a) : __sinf(a));
                    ((u16*)Cout)[(size_t)(bb*SEQ + 1 + pos)*256 + col] = f2bf(v + pe);
                } else if (OUTBF) {
                    ((u16*)Cout)[(size_t)row*N + col] = f2bf(v);
                } else {
                    ((float*)Cout)[(size_t)row*N + col] = v;
                }
            }
        }
    }
}

// ---------------------------------------------------------------------------
// LayerNorm over D=512, bf16 out; grid TOK, block 256
__global__ void ln_kernel(const float* __restrict__ x, const float* __restrict__ g,
                          const float* __restrict__ bta, u16* __restrict__ out) {
    int t = blockIdx.x;
    int tid = threadIdx.x;
    const float* xr = x + (size_t)t*DIM;
    float v0 = xr[tid], v1 = xr[tid+256];
    float s = v0 + v1, sq = v0*v0 + v1*v1;
    __shared__ float rs[4], rq[4];
    for (int off = 32; off; off >>= 1) { s += __shfl_down(s, off); sq += __shfl_down(sq, off); }
    int wid = tid >> 6, lane = tid & 63;
    if (lane == 0) { rs[wid] = s; rq[wid] = sq; }
    __syncthreads();
    __shared__ float mean_s, rstd_s;
    if (tid == 0) {
        float ts = rs[0]+rs[1]+rs[2]+rs[3], tq = rq[0]+rq[1]+rq[2]+rq[3];
        float m = ts / DIM;
        float var = tq / DIM - m*m;
        mean_s = m; rstd_s = rsqrtf(var + 1e-5f);
    }
    __syncthreads();
    float m = mean_s, r = rstd_s;
    out[(size_t)t*DIM + tid]       = f2bf((v0 - m)*r*g[tid]     + bta[tid]);
    out[(size_t)t*DIM + tid + 256] = f2bf((v1 - m)*r*g[tid+256] + bta[tid+256]);
}

// ---------------------------------------------------------------------------
// Fully fused attention per batch b (512 threads = 8 waves):
//  (a) wave h computes S_h = softmax_k(Q_h K_h^T / 8) via MFMA -> s_lds [208][28]
//  (b) vw[k,r] = sum_d2 V[k,r*64+d2]*sw[d2]   (416 threads, shfl-pair reduce)
//  (c) e[hq,r] = sum_k s*vw; comp = softmax_r(e)   (qv & score_b cancel)
//  (d) o[(h,q),d2] = sum_kr (s*comp) @ Vflat  via MFMA (K=208 pad 224)
__global__ __launch_bounds__(512) void attn_fused_kernel(const u16* __restrict__ qkv,
                                                         const float* __restrict__ score_w,
                                                         u16* __restrict__ attn_o) {
    int b = blockIdx.x;
    __shared__ u16 Bt[64*224];        // V as [d2][kr], byte ^= (d2&7)<<4
    __shared__ float s_lds[208*28];   // [(h*26+q)][k], k 26..27 = 0
    __shared__ float vwl[208];        // [k*8+r]
    __shared__ float cmp_lds[208*8];  // [(h,q)][r]
    __shared__ float swl[64];
    int tid = threadIdx.x;
    int lane = tid & 63, w = tid >> 6;

    if (tid < 64) swl[tid] = score_w[32 + tid];
    // V -> Bt (transpose to [d2][kr]); coalesced global bf16 reads
    for (int k = 0; k < 26; ++k) {
        int d2 = tid & 63, r = tid >> 6;
        u16 v = qkv[(size_t)(b*SEQ+k)*1536 + 1024 + tid];
        int bo = (d2*448 + (k*8+r)*2) ^ ((d2 & 7) << 4);
        *(u16*)((char*)Bt + bo) = v;
    }
    {   // zero-pad kr 208..223
        int d2 = tid & 63, kr = 208 + (tid >> 6);
        int bo1 = (d2*448 + kr*2)     ^ ((d2 & 7) << 4);
        int bo2 = (d2*448 + (kr+8)*2) ^ ((d2 & 7) << 4);
        *(u16*)((char*)Bt + bo1) = 0;
        *(u16*)((char*)Bt + bo2) = 0;
    }
    // zero-pad s_lds cols 26,27
    for (int row = tid; row < 208; row += 512) {
        s_lds[row*28 + 26] = 0.f; s_lds[row*28 + 27] = 0.f;
    }

    // ---- (a) QK^T + softmax, wave w handles head h=w ----
    {
        int h = w;
        int col16 = lane & 15, ch = lane >> 4;
        short8_t qf[2][2], kf[2][2];
        #pragma unroll
        for (int mi = 0; mi < 2; ++mi) {
            int q = mi*16 + col16;
            #pragma unroll
            for (int kk = 0; kk < 2; ++kk) {
                if (q < 26)
                    qf[mi][kk] = *(const short8_t*)&qkv[(size_t)(b*SEQ+q)*1536 + h*64 + kk*32 + ch*8];
                else
                    qf[mi][kk] = (short8_t){0,0,0,0,0,0,0,0};
            }
        }
        #pragma unroll
        for (int ni = 0; ni < 2; ++ni) {
            int kq = ni*16 + col16;
            #pragma unroll
            for (int kk = 0; kk < 2; ++kk) {
                if (kq < 26)
                    kf[ni][kk] = *(const short8_t*)&qkv[(size_t)(b*SEQ+kq)*1536 + 512 + h*64 + kk*32 + ch*8];
                else
                    kf[ni][kk] = (short8_t){0,0,0,0,0,0,0,0};
            }
        }
        floatx4 sacc[2][2];
        #pragma unroll
        for (int mi = 0; mi < 2; ++mi)
            #pragma unroll
            for (int ni = 0; ni < 2; ++ni)
                sacc[mi][ni] = (floatx4){0.f,0.f,0.f,0.f};
        #pragma unroll
        for (int kk = 0; kk < 2; ++kk)
            #pragma unroll
            for (int mi = 0; mi < 2; ++mi)
                #pragma unroll
                for (int ni = 0; ni < 2; ++ni)
                    sacc[mi][ni] = __builtin_amdgcn_mfma_f32_16x16x32_bf16(
                        qf[mi][kk], kf[ni][kk], sacc[mi][ni], 0, 0, 0);
        #pragma unroll
        for (int mi = 0; mi < 2; ++mi) {
            #pragma unroll
            for (int r = 0; r < 4; ++r) {
                float s0 = sacc[mi][0][r] * 0.125f;
                float s1 = (col16 < 10) ? sacc[mi][1][r] * 0.125f : -1e30f;
                float mx = fmaxf(s0, s1);
                #pragma unroll
                for (int msk = 1; msk < 16; msk <<= 1) mx = fmaxf(mx, __shfl_xor(mx, msk));
                float e0 = __expf(s0 - mx);
                float e1 = (col16 < 10) ? __expf(s1 - mx) : 0.f;
                float den = e0 + e1;
                #pragma unroll
                for (int msk = 1; msk < 16; msk <<= 1) den += __shfl_xor(den, msk);
                float inv = 1.f / den;
                int q = mi*16 + ch*4 + r;
                if (q < 26) {
                    s_lds[(h*26+q)*28 + col16] = e0 * inv;
                    if (col16 < 10) s_lds[(h*26+q)*28 + 16 + col16] = e1 * inv;
                }
            }
        }
    }
    __syncthreads();

    // ---- (b) vw: 416 threads, each sums half the d2 range; pair-reduce ----
    if (tid < 416) {
        int kr = tid >> 1, h0 = (tid & 1) * 32;
        float acc = 0.f;
        #pragma unroll
        for (int dd = 0; dd < 32; ++dd) {
            int d2 = h0 + dd;
            int bo = (d2*448 + kr*2) ^ ((d2 & 7) << 4);
            acc += bf2f(*(const u16*)((const char*)Bt + bo)) * swl[d2];
        }
        acc += __shfl_xor(acc, 1);
        if ((tid & 1) == 0) vwl[kr] = acc;
    }
    __syncthreads();

    // ---- (c) e + softmax over r ----
    if (tid < 208) {
        float srow[26];
        #pragma unroll
        for (int k = 0; k < 26; ++k) srow[k] = s_lds[tid*28 + k];
        float e[8];
        #pragma unroll
        for (int r = 0; r < 8; ++r) {
            float a = 0.f;
            #pragma unroll
            for (int k = 0; k < 26; ++k) a += srow[k] * vwl[k*8 + r];
            e[r] = a;
        }
        float m = e[0];
        #pragma unroll
        for (int r = 1; r < 8; ++r) m = fmaxf(m, e[r]);
        float den = 0.f;
        #pragma unroll
        for (int r = 0; r < 8; ++r) { e[r] = __expf(e[r]-m); den += e[r]; }
        float inv = 1.f/den;
        #pragma unroll
        for (int r = 0; r < 8; ++r) cmp_lds[tid*8+r] = e[r]*inv;
    }
    __syncthreads();

    // ---- (d) MFMA: C[208][64] = w2[208][224] @ Vflat[224][64] ----
    int mh = w >> 2, nt = w & 3;
    int ntile0 = nt*16;
    short8_t bfr[7];
    #pragma unroll
    for (int ks = 0; ks < 7; ++ks) {
        int col = ntile0 + (lane & 15);
        int krb = ks*32 + (lane >> 4)*8;
        int bo = (col*448 + krb*2) ^ ((col & 7) << 4);
        bfr[ks] = *(const short8_t*)((const char*)Bt + bo);
    }
    int mt0 = mh ? 7 : 0, mt1 = mh ? 13 : 7;
    for (int mt = mt0; mt < mt1; ++mt) {
        int arow = mt*16 + (lane & 15);
        float c8[8];
        #pragma unroll
        for (int r = 0; r < 8; ++r) c8[r] = cmp_lds[arow*8 + r];
        floatx4 acc = (floatx4){0.f,0.f,0.f,0.f};
        #pragma unroll
        for (int ks = 0; ks < 7; ++ks) {
            int k = ks*4 + (lane >> 4);
            float sv = s_lds[arow*28 + k];
            short8_t af;
            #pragma unroll
            for (int j = 0; j < 8; ++j) af[j] = (short)f2bf(sv * c8[j]);
            acc = __builtin_amdgcn_mfma_f32_16x16x32_bf16(af, bfr[ks], acc, 0, 0, 0);
        }
        int colg = ntile0 + (lane & 15);
        #pragma unroll
        for (int rr = 0; rr < 4; ++rr) {
            int rowg = mt*16 + (lane >> 4)*4 + rr;
            int h = rowg / 26, q = rowg - h*26;
            attn_o[(size_t)(b*SEQ+q)*DIM + h*64 + colg] = f2bf(acc[rr]);
        }
    }
}

// ---------------------------------------------------------------------------
// head: y = x[:,0,:]@out_w+out_b; log_softmax. grid B, block 256, d-parallel.
__global__ void head_kernel(const float* __restrict__ x, const float* __restrict__ out_w,
                            const float* __restrict__ out_b, float* __restrict__ y) {
    int b = blockIdx.x;
    int tid = threadIdx.x;
    const float* xr = x + (size_t)(b*SEQ)*DIM;
    float x0 = xr[tid], x1 = xr[tid+256];
    float part[10];
    #pragma unroll
    for (int c = 0; c < 10; ++c)
        part[c] = x0*out_w[tid*10 + c] + x1*out_w[(tid+256)*10 + c];
    #pragma unroll
    for (int off = 32; off; off >>= 1)
        #pragma unroll
        for (int c = 0; c < 10; ++c) part[c] += __shfl_down(part[c], off);
    __shared__ float red[4][10];
    __shared__ float yv[10];
    int wid = tid >> 6, lane = tid & 63;
    if (lane == 0)
        #pragma unroll
        for (int c = 0; c < 10; ++c) red[wid][c] = part[c];
    __syncthreads();
    if (tid < 10)
        yv[tid] = out_b[tid] + red[0][tid] + red[1][tid] + red[2][tid] + red[3][tid];
    __syncthreads();
    if (tid < 10) {
        float m = yv[0];
        #pragma unroll
        for (int i = 1; i < 10; ++i) m = fmaxf(m, yv[i]);
        float den = 0.0f;
        #pragma unroll
        for (int i = 0; i < 10; ++i) den += __expf(yv[i]-m);
        y[b*10 + tid] = yv[tid] - m - __logf(den);
    }
}

// ---------------------------------------------------------------------------
extern "C" void kernel_launch(void* const* d_in, const int* in_sizes, int n_in,
                              void* d_out, int out_size, void* d_ws, size_t ws_size,
                              hipStream_t stream) {
    const float* img      = (const float*)d_in[0];
    const float* qst      = (const float*)d_in[1];
    const float* conv_w   = (const float*)d_in[2];
    const float* conv_b   = (const float*)d_in[3];
    const float* qrep_w   = (const float*)d_in[4];
    const float* qrep_b   = (const float*)d_in[5];
    const float* cls_tok  = (const float*)d_in[6];
    const float* map_w    = (const float*)d_in[7];
    const float* map_b    = (const float*)d_in[8];
    const float* norm1_g  = (const float*)d_in[9];
    const float* norm1_b  = (const float*)d_in[10];
    const float* norm2_g  = (const float*)d_in[11];
    const float* norm2_b  = (const float*)d_in[12];
    const float* q_w      = (const float*)d_in[13];
    const float* q_b      = (const float*)d_in[14];
    const float* k_w      = (const float*)d_in[15];
    const float* k_b      = (const float*)d_in[16];
    const float* v_w      = (const float*)d_in[17];
    const float* v_b      = (const float*)d_in[18];
    // d_in[19] qv_w, d_in[20] qv_b: cancel in r-softmax — unused
    const float* score_w  = (const float*)d_in[21];
    // d_in[22] score_b: constant along softmax axis — unused
    const float* final_w  = (const float*)d_in[23];
    const float* final_b  = (const float*)d_in[24];
    const float* ffn1_w   = (const float*)d_in[25];
    const float* ffn1_b   = (const float*)d_in[26];
    const float* ffn2_w   = (const float*)d_in[27];
    const float* ffn2_b   = (const float*)d_in[28];
    const float* out_w    = (const float*)d_in[29];
    const float* out_b    = (const float*)d_in[30];

    float* ws = (float*)d_ws;
    size_t o = 0;
    float* x    = ws + o;       o += (size_t)TOK*DIM;
    u16* qkvT   = (u16*)(ws+o); o += (size_t)1536*512/2;
    u16* finT   = (u16*)(ws+o); o += (size_t)512*512/2;
    u16* f1T    = (u16*)(ws+o); o += (size_t)1024*512/2;
    u16* f2T    = (u16*)(ws+o); o += (size_t)512*1024/2;
    u16* mapT   = (u16*)(ws+o); o += (size_t)512*256/2;
    u16* cwT    = (u16*)(ws+o); o += (size_t)256*704/2;
    float* qkvb = ws + o;       o += 1536;
    float* r2   = ws + o;
    // phase-2 layout in r2
    u16*  h_bf    = (u16*)r2;                                  // TOK*512 bf16
    u16*  qkv_bf  = (u16*)(r2 + (size_t)TOK*DIM/2);            // TOK*1536 bf16
    u16*  attn_obf= (u16*)(r2 + (size_t)TOK*DIM/2 + (size_t)TOK*1536/2); // TOK*512 bf16
    u16*  ffbuf   = qkv_bf;                                    // alias (qkv dead in FFN)
    // phase-1 aliases r2
    u16*  Pbuf    = (u16*)r2;                                  // 6400*704 bf16
    u16*  emb_bf  = (u16*)(r2 + (size_t)6400*704/2);           // TOK*256 bf16
    float* quem   = r2 + (size_t)6400*704/2 + (size_t)TOK*256/2;

    // ---- weight prep + cls rows + question path: one dispatch ----
    prep_all<<<1313, 256, 0, stream>>>(q_w, k_w, v_w, final_w, ffn1_w, ffn2_w, map_w, conv_w,
                                       q_b, k_b, v_b, cls_tok, qst, qrep_w, qrep_b, map_b,
                                       qkvT, finT, f1T, f2T, mapT, cwT, qkvb, emb_bf, quem);

    // ---- phase 1: embedding ----
    im2col_kernel<<<6400, 256, 0, stream>>>(img, Pbuf);
    // conv patch-GEMM writes emb rows directly (+pe), bf16
    mfma_gemm<64,3,0,1><<<dim3(2,100), dim3(512), 0, stream>>>(
        Pbuf, cwT, conv_b, nullptr, emb_bf, 6400, 256, 704, 1.0f);
    mfma_gemm<64,2,0,0><<<dim3(4,104), dim3(512), 0, stream>>>(
        emb_bf, mapT, nullptr, quem, x, TOK, 512, 256, 1.0f);

    // ---- phase 2: 4 transformer iterations ----
    for (int it = 0; it < 4; ++it) {
        ln_kernel<<<TOK, 256, 0, stream>>>(x, norm1_g, norm1_b, h_bf);
        mfma_gemm<128,0,0,1><<<dim3(12,52), dim3(512), 0, stream>>>(
            h_bf, qkvT, qkvb, nullptr, qkv_bf, TOK, 1536, 512, 1.0f);
        attn_fused_kernel<<<NB, 512, 0, stream>>>(qkv_bf, score_w, attn_obf);
        mfma_gemm<64,1,0,0><<<dim3(4,104), dim3(512), 0, stream>>>(
            attn_obf, finT, final_b, x, x, TOK, 512, 512, 1.0f);
        ln_kernel<<<TOK, 256, 0, stream>>>(x, norm2_g, norm2_b, h_bf);
        mfma_gemm<128,0,1,1><<<dim3(8,52), dim3(512), 0, stream>>>(
            h_bf, f1T, ffn1_b, nullptr, ffbuf, TOK, 1024, 512, 1.0f);
        mfma_gemm<64,1,0,0><<<dim3(4,104), dim3(512), 0, stream>>>(
            ffbuf, f2T, ffn2_b, x, x, TOK, 512, 1024, 1.0f);
    }

    head_kernel<<<NB, 256, 0, stream>>>(x, out_w, out_b, (float*)d_out);
}